// Round 10
// baseline (95.112 us; speedup 1.0000x reference)
//
#include <hip/hip_runtime.h>
#include <stdint.h>

#define NXP   2048   // pivotal (source) nodes
#define NC    16     // feature channels
#define GD    8      // grid cells per axis
#define NCELL (GD*GD*GD)   // 512
#define CAP   512    // max staged candidates per cell (multiple of 8)
#define HCELL 0.125f // cell width
#define HB    128    // query histogram blocks (x512 threads = 65536)

// ---- d_ws layout (bytes); total need 309888 < 312832 (proven available r9) ----
#define WS_SPT    0         // float4[2048]
#define WS_SIDX   32768     // int[2048]
#define WS_CST    40960     // int[513]
#define WS_QB2D   43520     // ushort[HB][512] private query histograms
#define WS_QSTART 174592    // int[513]
#define WS_QCUR   176704    // int[512]
#define WS_FLAG   178752    // int
#define WS_QIDX   178816    // ushort[65536]
#define WS_NEED   309888

__device__ __forceinline__ int cell_of(float v) {
    int c = (int)(v * (float)GD);
    c = c > GD - 1 ? GD - 1 : c;
    return c < 0 ? 0 : c;
}

__device__ __forceinline__ uint32_t mono(float d) {
    uint32_t b = __float_as_uint(d);
    return b ^ (uint32_t)(((int32_t)b >> 31) | 0x80000000);
}
__device__ __forceinline__ float unmono(uint32_t m) {
    uint32_t b = (m & 0x80000000u) ? (m ^ 0x80000000u) : ~m;
    return __uint_as_float(b);
}

__device__ __forceinline__ void ins_fast(uint64_t k, uint64_t& b0, uint64_t& b1, uint64_t& b2) {
    const bool lt0 = k < b0, lt1 = k < b1;
    b2 = lt1 ? b1 : k;
    b1 = lt0 ? b0 : (lt1 ? k : b1);
    b0 = lt0 ? k  : b0;
}
__device__ __forceinline__ void ins_dedup(uint64_t k, uint64_t& b0, uint64_t& b1, uint64_t& b2) {
    if (k == b0 || k == b1 || k == b2) return;
    const bool lt0 = k < b0, lt1 = k < b1, lt2 = k < b2;
    b2 = lt1 ? b1 : (lt2 ? k : b2);
    b1 = lt0 ? b0 : (lt1 ? k : b1);
    b0 = lt0 ? k  : b0;
}
__device__ __forceinline__ uint64_t shfl_u64(uint64_t v, int src) {
    const int lo = __shfl((int)(uint32_t)v, src);
    const int hi = __shfl((int)(uint32_t)(v >> 32), src);
    return ((uint64_t)(uint32_t)hi << 32) | (uint32_t)lo;
}
__device__ __forceinline__ uint64_t shfl_xor_u64(uint64_t v, int mask) {
    const int lo = __shfl_xor((int)(uint32_t)v, mask);
    const int hi = __shfl_xor((int)(uint32_t)(v >> 32), mask);
    return ((uint64_t)(uint32_t)hi << 32) | (uint32_t)lo;
}

// ========== k1: block 0 builds point grid; blocks 1..nqb do query hists ==========
__global__ __launch_bounds__(512) void build_hist(
    const float* __restrict__ pos_x, const float* __restrict__ pos_y, int ny,
    float4* __restrict__ wspt, int* __restrict__ wsidx, int* __restrict__ wcstart,
    unsigned short* __restrict__ qb2d, int* __restrict__ flag, int nqb)
{
    __shared__ int sA[NCELL];
    __shared__ int sB[NCELL];
    const int t = threadIdx.x;

    if (blockIdx.x == 0) {
        // ---- point grid build (proven round-6/7/9 code) ----
        sA[t] = 0;
        if (t == 0 && flag) atomicExch(flag, 0);   // reset handshake for k2
        __syncthreads();

        const float4* px4 = (const float4*)pos_x;
        const float4 v0 = px4[t*3+0], v1 = px4[t*3+1], v2 = px4[t*3+2];
        const float pxx[4] = {v0.x, v0.w, v1.z, v2.y};
        const float pyy[4] = {v0.y, v1.x, v1.w, v2.z};
        const float pzz[4] = {v0.z, v1.y, v2.x, v2.w};
        int cc[4];
        #pragma unroll
        for (int i = 0; i < 4; ++i) {
            cc[i] = (cell_of(pzz[i]) * GD + cell_of(pyy[i])) * GD + cell_of(pxx[i]);
            atomicAdd(&sA[cc[i]], 1);
        }
        __syncthreads();

        if (t < 64) {
            const int base = t * 8;
            int v[8];
            int run = 0;
            #pragma unroll
            for (int i = 0; i < 8; ++i) { run += sA[base + i]; v[i] = run; }
            int xs = run;
            #pragma unroll
            for (int off = 1; off < 64; off <<= 1) {
                const int y = __shfl_up(xs, off);
                if (t >= off) xs += y;
            }
            const int excl = xs - run;
            #pragma unroll
            for (int i = 0; i < 8; ++i) {
                const int inc = excl + v[i];
                wcstart[base + i + 1] = inc;
                sB[base + i] = inc - sA[base + i];
            }
            if (t == 0) wcstart[0] = 0;
        }
        __syncthreads();

        #pragma unroll
        for (int i = 0; i < 4; ++i) {
            const int p = t * 4 + i;
            const int pos = atomicAdd(&sB[cc[i]], 1);
            const float sx = __fadd_rn(__fadd_rn(__fmul_rn(pxx[i], pxx[i]),
                                                 __fmul_rn(pyy[i], pyy[i])),
                                       __fmul_rn(pzz[i], pzz[i]));
            wspt[pos] = make_float4(pxx[i], pyy[i], pzz[i], sx);
            wsidx[pos] = p;
        }
    } else {
        // ---- private query histogram: block bq handles queries [bq*512, +512) ----
        const int bq = blockIdx.x - 1;
        sA[t] = 0;
        __syncthreads();
        const int q = bq * 512 + t;
        if (q < ny) {
            const int c = (cell_of(pos_y[q*3+2]) * GD + cell_of(pos_y[q*3+1])) * GD
                        + cell_of(pos_y[q*3+0]);
            atomicAdd(&sA[c], 1);
        }
        __syncthreads();
        qb2d[bq * NCELL + t] = (unsigned short)sA[t];
        (void)nqb;
    }
}

// ========== k2: block 0 scans bins + inits cursors; all blocks scatter ==========
__global__ __launch_bounds__(512) void qscan_scatter(
    const float* __restrict__ pos_y, int ny, int nqb,
    const unsigned short* __restrict__ qb2d,
    int* __restrict__ qstart, int* __restrict__ qcur, int* __restrict__ flag,
    unsigned short* __restrict__ qidx)
{
    __shared__ int sums[NCELL];
    const int t = threadIdx.x;

    if (blockIdx.x == 0) {
        int s = 0;
        for (int b = 0; b < nqb; ++b) s += qb2d[b * NCELL + t];
        sums[t] = s;
        __syncthreads();
        if (t < 64) {
            const int base = t * 8;
            int v[8];
            int run = 0;
            #pragma unroll
            for (int i = 0; i < 8; ++i) { run += sums[base + i]; v[i] = run; }
            int xs = run;
            #pragma unroll
            for (int off = 1; off < 64; off <<= 1) {
                const int y = __shfl_up(xs, off);
                if (t >= off) xs += y;
            }
            const int excl = xs - run;
            #pragma unroll
            for (int i = 0; i < 8; ++i) {
                const int inc = excl + v[i];
                qstart[base + i + 1] = inc;
                atomicExch(&qcur[base + i], inc - sums[base + i]);  // coherent init
            }
            if (t == 0) qstart[0] = 0;
        }
        __syncthreads();
        __threadfence();
        if (t == 0) atomicExch(flag, 1);   // release
    }

    // all blocks (incl. 0) wait for cursor init, then scatter their slice
    if (t == 0) {
        while (atomicAdd(flag, 0) == 0) __builtin_amdgcn_s_sleep(8);
    }
    __syncthreads();
    __threadfence();

    const int q = blockIdx.x * 512 + t;
    if (q < ny) {
        const int c = (cell_of(pos_y[q*3+2]) * GD + cell_of(pos_y[q*3+1])) * GD
                    + cell_of(pos_y[q*3+0]);
        const int pos = atomicAdd(&qcur[c], 1);
        qidx[pos] = (unsigned short)q;
    }
}

// ========== k4: one block per cell, lane per query, wave-uniform scan ==========
__global__ __launch_bounds__(128) void knn_cell(
    const float* __restrict__ x, const float* __restrict__ pos_x,
    const float* __restrict__ pos_y,
    const float4* __restrict__ wspt, const int* __restrict__ wsidx,
    const int* __restrict__ wcst,
    const int* __restrict__ qstart, const unsigned short* __restrict__ qidx,
    float* __restrict__ out)
{
    __shared__ float4 scand[CAP];
    __shared__ int    scidx[CAP];
    __shared__ int    rst[25], roff[26];
    __shared__ int    sL, sForce;

    const int t = threadIdx.x;
    const int c = blockIdx.x;
    const int cx = c & 7, cy = (c >> 3) & 7, cz = c >> 6;

    const int bcnt = (int)(cx == 0 || cx == GD-1) + (int)(cy == 0 || cy == GD-1)
                   + (int)(cz == 0 || cz == GD-1);
    const int R  = (bcnt >= 2) ? 2 : 1;
    const int W  = 2 * R + 1;
    const int NR = W * W;

    if (t < NR) {
        const int uz = cz + t / W - R, uy = cy + t % W - R;
        int st = 0, len = 0;
        if (((unsigned)uz < (unsigned)GD) & ((unsigned)uy < (unsigned)GD)) {
            const int xa = cx - R < 0 ? 0 : cx - R;
            const int xb = cx + R > GD - 1 ? GD - 1 : cx + R;
            const int cb = (uz * GD + uy) * GD;
            st  = wcst[cb + xa];
            len = wcst[cb + xb + 1] - st;
        }
        rst[t] = st;
        roff[t] = len;
    }
    __syncthreads();
    if (t == 0) {
        int o = 0;
        #pragma unroll 1
        for (int r = 0; r < NR; ++r) { const int l = roff[r]; roff[r] = o; o += l; }
        roff[NR] = o;
        sL = o > CAP ? CAP : o;
        sForce = (o > CAP) ? 1 : 0;
    }
    __syncthreads();

    const int L = sL, Lpad = (sL + 7) & ~7, force = sForce;
    for (int i = t; i < L; i += 128) {
        int r = 0;
        while (i >= roff[r + 1]) ++r;
        const int src = rst[r] + (i - roff[r]);
        scand[i] = wspt[src];
        scidx[i] = wsidx[src];
    }
    for (int i = L + t; i < Lpad; i += 128) {
        scand[i] = make_float4(0.f, 0.f, 0.f, 3e30f);  // sentinel (never beats real)
        scidx[i] = 0x7fffffff;
    }
    __syncthreads();

    const int wave = t >> 6, lane = t & 63;
    const int qs = qstart[c], qe = qstart[c + 1];

    for (int i0 = qs + wave * 64; i0 < qe; i0 += 128) {
        const int slot = i0 + lane;
        const bool active = slot < qe;
        const int q = active ? (int)qidx[slot] : 0;
        float y0 = 0.f, y1 = 0.f, y2 = 0.f;
        if (active) { y0 = pos_y[q*3+0]; y1 = pos_y[q*3+1]; y2 = pos_y[q*3+2]; }
        const float sy = __fadd_rn(__fadd_rn(__fmul_rn(y0, y0), __fmul_rn(y1, y1)),
                                   __fmul_rn(y2, y2));

        // exact clearance to the staged cube (domain-side faces -> no bound);
        // unstaged points have exact d2 >= clr^2; expanded-form skew <= ~4e-6
        // << 1e-4 margin -> staged superset provably contains reference top-3
        float clr = 1e30f;
        if (cx - R > 0)      clr = fminf(clr, y0 - (float)(cx - R) * HCELL);
        if (cx + R < GD - 1) clr = fminf(clr, (float)(cx + R + 1) * HCELL - y0);
        if (cy - R > 0)      clr = fminf(clr, y1 - (float)(cy - R) * HCELL);
        if (cy + R < GD - 1) clr = fminf(clr, (float)(cy + R + 1) * HCELL - y1);
        if (cz - R > 0)      clr = fminf(clr, y2 - (float)(cz - R) * HCELL);
        if (cz + R < GD - 1) clr = fminf(clr, (float)(cz + R + 1) * HCELL - y2);
        const float thr = clr * clr;

        uint64_t b0 = ~0ull, b1 = ~0ull, b2 = ~0ull;

        // phase A: wave-uniform broadcast scan, batch-8 for ILP; candidate d2
        // rounding identical to every passing round
        for (int j = 0; j < Lpad; j += 8) {
            #pragma unroll
            for (int u = 0; u < 8; ++u) {
                const float4 pt = scand[j + u];
                const int oi = scidx[j + u];
                const float dot = __fmaf_rn(y2, pt.z,
                                  __fmaf_rn(y1, pt.y, __fmul_rn(y0, pt.x)));
                const float d = __fmaf_rn(-2.0f, dot, __fadd_rn(sy, pt.w));
                const uint64_t kk = ((uint64_t)mono(d) << 32) | (uint32_t)oi;
                const bool lt0 = kk < b0, lt1 = kk < b1, lt2 = kk < b2;
                b2 = lt1 ? b1 : (lt2 ? kk : b2);
                b1 = lt0 ? b0 : (lt1 ? kk : b1);
                b0 = lt0 ? kk : b0;
            }
        }

        // escalation: wave-coop terminal brute force with dedup (complete)
        bool esc = false;
        if (active) {
            const bool have3 = (b2 != ~0ull);
            const float b2d = unmono((uint32_t)(b2 >> 32));
            esc = !(have3 && (b2d + 1e-4f < thr)) | (force != 0);
        }
        unsigned long long bal = __ballot(esc);
        while (bal) {
            const int e = __ffsll(bal) - 1;
            bal &= bal - 1;
            const float ey0 = __shfl(y0, e), ey1 = __shfl(y1, e), ey2 = __shfl(y2, e);
            const float esy = __shfl(sy, e);
            uint64_t m0 = shfl_u64(b0, e), m1 = shfl_u64(b1, e), m2 = shfl_u64(b2, e);
            for (int p = lane; p < NXP; p += 64) {
                const float4 pt = wspt[p];
                const float dot = __fmaf_rn(ey2, pt.z,
                                  __fmaf_rn(ey1, pt.y, __fmul_rn(ey0, pt.x)));
                const float d = __fmaf_rn(-2.0f, dot, __fadd_rn(esy, pt.w));
                const uint64_t kk = ((uint64_t)mono(d) << 32) | (uint32_t)wsidx[p];
                if (kk < m2) ins_dedup(kk, m0, m1, m2);
            }
            #pragma unroll
            for (int mask = 1; mask < 64; mask <<= 1) {
                const uint64_t r0 = shfl_xor_u64(m0, mask);
                const uint64_t r1 = shfl_xor_u64(m1, mask);
                const uint64_t r2 = shfl_xor_u64(m2, mask);
                ins_dedup(r0, m0, m1, m2);
                ins_dedup(r1, m0, m1, m2);
                ins_dedup(r2, m0, m1, m2);
            }
            if (lane == e) { b0 = m0; b1 = m1; b2 = m2; }
        }

        if (active) {
            const int j[3] = { (int)(uint32_t)b0, (int)(uint32_t)b1, (int)(uint32_t)b2 };
            float w[3];
            #pragma unroll
            for (int i = 0; i < 3; ++i) {
                const int jj = j[i];
                const float ax = pos_x[jj*3+0], ay = pos_x[jj*3+1], az = pos_x[jj*3+2];
                const float dx = __fsub_rn(ax, y0);
                const float dy = __fsub_rn(ay, y1);
                const float dz = __fsub_rn(az, y2);
                const float sq = __fadd_rn(__fadd_rn(__fmul_rn(dx, dx), __fmul_rn(dy, dy)),
                                           __fmul_rn(dz, dz));
                w[i] = 1.0f / fmaxf(sq, 1e-16f);
            }
            const float inv_den = 1.0f / __fadd_rn(__fadd_rn(w[0], w[1]), w[2]);

            const float4* x4 = (const float4*)x;
            float4* o4 = (float4*)out;
            #pragma unroll
            for (int tt = 0; tt < 4; ++tt) {
                const float4 a = x4[j[0]*4 + tt];
                const float4 b = x4[j[1]*4 + tt];
                const float4 cc2 = x4[j[2]*4 + tt];
                float4 r;
                r.x = (w[0]*a.x + w[1]*b.x + w[2]*cc2.x) * inv_den;
                r.y = (w[0]*a.y + w[1]*b.y + w[2]*cc2.y) * inv_den;
                r.z = (w[0]*a.z + w[1]*b.z + w[2]*cc2.z) * inv_den;
                r.w = (w[0]*a.w + w[1]*b.w + w[2]*cc2.w) * inv_den;
                o4[q*4 + tt] = r;
            }
        }
    }
}

// =============== fallback (round-7 kernel, 43 KB ws; proven 34 us) ===============
#define QBLK  512
#define SEG   8
#define QPB   (QBLK / SEG)
#define QGRID 512

__device__ __forceinline__ void merge_group8(uint64_t& b0, uint64_t& b1, uint64_t& b2) {
    #pragma unroll
    for (int mask = 1; mask < SEG; mask <<= 1) {
        const uint64_t r0 = shfl_xor_u64(b0, mask);
        const uint64_t r1 = shfl_xor_u64(b1, mask);
        const uint64_t r2 = shfl_xor_u64(b2, mask);
        ins_dedup(r0, b0, b1, b2);
        ins_dedup(r1, b0, b1, b2);
        ins_dedup(r2, b0, b1, b2);
    }
}

__global__ __launch_bounds__(QBLK) void knn_query_fb(
    const float* __restrict__ x, const float* __restrict__ pos_x,
    const float* __restrict__ pos_y,
    const float4* __restrict__ wspt, const int* __restrict__ wsidx,
    const int* __restrict__ wcstart,
    float* __restrict__ out, int ny)
{
    __shared__ float4 spt[NXP];
    __shared__ int    sidx[NXP];
    __shared__ int    cstart[NCELL + 1];

    const int t = threadIdx.x;
    for (int i = t; i < NXP; i += QBLK) spt[i] = wspt[i];
    for (int i = t; i < NXP; i += QBLK) sidx[i] = wsidx[i];
    for (int i = t; i < NCELL + 1; i += QBLK) cstart[i] = wcstart[i];
    __syncthreads();

    const int s = t & (SEG - 1);
    const int nbatch = (ny + QPB - 1) / QPB;

    for (int batch = blockIdx.x; batch < nbatch; batch += gridDim.x) {
        const int q = batch * QPB + (t >> 3);
        if (q >= ny) continue;

        const float y0 = pos_y[q*3+0], y1 = pos_y[q*3+1], y2 = pos_y[q*3+2];
        const float sy = __fadd_rn(__fadd_rn(__fmul_rn(y0, y0), __fmul_rn(y1, y1)),
                                   __fmul_rn(y2, y2));
        const int cx = cell_of(y0), cy = cell_of(y1), cz = cell_of(y2);

        uint64_t b0 = ~0ull, b1 = ~0ull, b2 = ~0ull;

#define EVAL_BODY(P, INS)                                                       \
        {                                                                       \
            const float4 pt = spt[P];                                           \
            const float dot = __fmaf_rn(y2, pt.z,                               \
                              __fmaf_rn(y1, pt.y, __fmul_rn(y0, pt.x)));        \
            const float d = __fmaf_rn(-2.0f, dot, __fadd_rn(sy, pt.w));         \
            const uint64_t kk = ((uint64_t)mono(d) << 32) | (uint32_t)sidx[P];  \
            if (kk < b2) INS(kk, b0, b1, b2);                                   \
        }

        const int x0 = cx - 1 < 0 ? 0 : cx - 1;
        const int x1 = cx + 1 > GD - 1 ? GD - 1 : cx + 1;
        #pragma unroll
        for (int r = 0; r < 9; ++r) {
            const int uz = cz + r / 3 - 1, uy = cy + r % 3 - 1;
            int st = 0, en = 0;
            if (((unsigned)uz < (unsigned)GD) & ((unsigned)uy < (unsigned)GD)) {
                const int cb = (uz * GD + uy) * GD;
                st = cstart[cb + x0];
                en = cstart[cb + x1 + 1];
            }
            for (int p = st + s; p < en; p += SEG) EVAL_BODY(p, ins_fast)
        }
        merge_group8(b0, b1, b2);

        {
            bool have3 = (b2 != ~0ull);
            float b2d = unmono((uint32_t)(b2 >> 32));
            if (!(have3 && (b2d + 1e-4f < 0.015625f))) {
                for (int r = 0; r < 25; ++r) {
                    const int dzi = r / 5 - 2, dyi = r % 5 - 2;
                    const int uz = cz + dzi, uy = cy + dyi;
                    if (((unsigned)uz >= (unsigned)GD) | ((unsigned)uy >= (unsigned)GD))
                        continue;
                    const int cb = (uz * GD + uy) * GD;
                    if (dzi == -2 || dzi == 2 || dyi == -2 || dyi == 2) {
                        const int xa = cx - 2 < 0 ? 0 : cx - 2;
                        const int xb = cx + 2 > GD - 1 ? GD - 1 : cx + 2;
                        const int st = cstart[cb + xa], en = cstart[cb + xb + 1];
                        for (int p = st + s; p < en; p += SEG) EVAL_BODY(p, ins_fast)
                    } else {
                        if (cx - 2 >= 0) {
                            const int st = cstart[cb + cx - 2], en = cstart[cb + cx - 1];
                            for (int p = st + s; p < en; p += SEG) EVAL_BODY(p, ins_fast)
                        }
                        if (cx + 2 <= GD - 1) {
                            const int st = cstart[cb + cx + 2], en = cstart[cb + cx + 3];
                            for (int p = st + s; p < en; p += SEG) EVAL_BODY(p, ins_fast)
                        }
                    }
                }
                merge_group8(b0, b1, b2);

                have3 = (b2 != ~0ull);
                b2d = unmono((uint32_t)(b2 >> 32));
                if (!(have3 && (b2d + 1e-4f < 0.0625f))) {
                    for (int p = s; p < NXP; p += SEG) EVAL_BODY(p, ins_dedup)
                    merge_group8(b0, b1, b2);
                }
            }
        }
#undef EVAL_BODY

        const int j[3] = { (int)(uint32_t)b0, (int)(uint32_t)b1, (int)(uint32_t)b2 };
        float w[3];
        #pragma unroll
        for (int i = 0; i < 3; ++i) {
            const int jj = j[i];
            const float ax = pos_x[jj*3+0], ay = pos_x[jj*3+1], az = pos_x[jj*3+2];
            const float dx = __fsub_rn(ax, y0);
            const float dy = __fsub_rn(ay, y1);
            const float dz = __fsub_rn(az, y2);
            const float sq = __fadd_rn(__fadd_rn(__fmul_rn(dx, dx), __fmul_rn(dy, dy)),
                                       __fmul_rn(dz, dz));
            w[i] = 1.0f / fmaxf(sq, 1e-16f);
        }
        const float inv_den = 1.0f / __fadd_rn(__fadd_rn(w[0], w[1]), w[2]);

        const float2* x2 = (const float2*)x;
        float2* o2 = (float2*)out;
        const float2 a = x2[j[0]*8 + s];
        const float2 b = x2[j[1]*8 + s];
        const float2 c = x2[j[2]*8 + s];
        float2 rr;
        rr.x = (w[0]*a.x + w[1]*b.x + w[2]*c.x) * inv_den;
        rr.y = (w[0]*a.y + w[1]*b.y + w[2]*c.y) * inv_den;
        o2[q*8 + s] = rr;
    }
}

extern "C" void kernel_launch(void* const* d_in, const int* in_sizes, int n_in,
                              void* d_out, int out_size, void* d_ws, size_t ws_size,
                              hipStream_t stream) {
    const float* x     = (const float*)d_in[0];  // [2048, 16]
    const float* pos_x = (const float*)d_in[1];  // [2048, 3]
    const float* pos_y = (const float*)d_in[2];  // [65536, 3]
    float* out = (float*)d_out;
    const int ny = in_sizes[2] / 3;  // 65536

    float4*         wspt   = (float4*)        ((char*)d_ws + WS_SPT);
    int*            wsidx  = (int*)           ((char*)d_ws + WS_SIDX);
    int*            wcst   = (int*)           ((char*)d_ws + WS_CST);
    unsigned short* qb2d   = (unsigned short*)((char*)d_ws + WS_QB2D);
    int*            qstart = (int*)           ((char*)d_ws + WS_QSTART);
    int*            qcur   = (int*)           ((char*)d_ws + WS_QCUR);
    int*            flag   = (int*)           ((char*)d_ws + WS_FLAG);
    unsigned short* qidx   = (unsigned short*)((char*)d_ws + WS_QIDX);

    const int nqb = (ny + 511) / 512;

    if (ws_size >= (size_t)WS_NEED && ny <= 65536 && nqb <= HB) {
        build_hist<<<1 + nqb, 512, 0, stream>>>(pos_x, pos_y, ny, wspt, wsidx, wcst,
                                                qb2d, flag, nqb);
        qscan_scatter<<<nqb, 512, 0, stream>>>(pos_y, ny, nqb, qb2d,
                                               qstart, qcur, flag, qidx);
        knn_cell<<<NCELL, 128, 0, stream>>>(x, pos_x, pos_y, wspt, wsidx, wcst,
                                            qstart, qidx, out);
    } else {
        build_hist<<<1, 512, 0, stream>>>(pos_x, pos_y, ny, wspt, wsidx, wcst,
                                          qb2d, (int*)nullptr, 0);
        knn_query_fb<<<QGRID, QBLK, 0, stream>>>(x, pos_x, pos_y, wspt, wsidx, wcst,
                                                 out, ny);
    }
}

// Round 11
// 59.404 us; speedup vs baseline: 1.6011x; 1.6011x over previous
//
#include <hip/hip_runtime.h>
#include <stdint.h>

#define NXP   2048   // pivotal (source) nodes
#define NC    16     // feature channels
#define GD    8      // grid cells per axis
#define NCELL (GD*GD*GD)   // 512
#define CAP   512    // max staged candidates per cell block
#define CAPQ  252    // query bucket capacity per cell (mean 128, ~11 sigma)
#define OVCAP 4096   // overflow list capacity
#define OVB   8      // overflow-processing blocks
#define HCELL 0.125f

// ---- d_ws layout (bytes); total 311424 <= 312832 (proven available, r9) ----
#define WS_SPT    0         // float4[2048]
#define WS_SIDX   32768     // int[2048]
#define WS_CST    40960     // int[513]
#define WS_QCNT   43072     // int[512]   per-cell query counts (zeroed per call)
#define WS_OVCNT  45120     // int        overflow count (zeroed per call)
#define WS_OVL    45184     // ushort[OVCAP]
#define WS_QBUF   53376     // ushort[512*CAPQ]
#define WS_NEED   311424

__device__ __forceinline__ int cell_of(float v) {
    int c = (int)(v * (float)GD);
    c = c > GD - 1 ? GD - 1 : c;
    return c < 0 ? 0 : c;
}
__device__ __forceinline__ uint32_t mono(float d) {
    uint32_t b = __float_as_uint(d);
    return b ^ (uint32_t)(((int32_t)b >> 31) | 0x80000000);
}
__device__ __forceinline__ float unmono(uint32_t m) {
    uint32_t b = (m & 0x80000000u) ? (m ^ 0x80000000u) : ~m;
    return __uint_as_float(b);
}
__device__ __forceinline__ void ins_fast(uint64_t k, uint64_t& b0, uint64_t& b1, uint64_t& b2) {
    const bool lt0 = k < b0, lt1 = k < b1;
    b2 = lt1 ? b1 : k;
    b1 = lt0 ? b0 : (lt1 ? k : b1);
    b0 = lt0 ? k  : b0;
}
__device__ __forceinline__ void ins_dedup(uint64_t k, uint64_t& b0, uint64_t& b1, uint64_t& b2) {
    if (k == b0 || k == b1 || k == b2) return;
    const bool lt0 = k < b0, lt1 = k < b1, lt2 = k < b2;
    b2 = lt1 ? b1 : (lt2 ? k : b2);
    b1 = lt0 ? b0 : (lt1 ? k : b1);
    b0 = lt0 ? k  : b0;
}
__device__ __forceinline__ uint64_t shfl_u64(uint64_t v, int src) {
    const int lo = __shfl((int)(uint32_t)v, src);
    const int hi = __shfl((int)(uint32_t)(v >> 32), src);
    return ((uint64_t)(uint32_t)hi << 32) | (uint32_t)lo;
}
__device__ __forceinline__ uint64_t shfl_xor_u64(uint64_t v, int mask) {
    const int lo = __shfl_xor((int)(uint32_t)v, mask);
    const int hi = __shfl_xor((int)(uint32_t)(v >> 32), mask);
    return ((uint64_t)(uint32_t)hi << 32) | (uint32_t)lo;
}

// shared epilogue: exact-diff weights (reference numerics) + 16-channel write
__device__ __forceinline__ void write_out_full(
    const float* __restrict__ x, const float* __restrict__ pos_x,
    float* __restrict__ out, int q, float y0, float y1, float y2,
    uint64_t b0, uint64_t b1, uint64_t b2)
{
    const int j[3] = { (int)(uint32_t)b0, (int)(uint32_t)b1, (int)(uint32_t)b2 };
    float w[3];
    #pragma unroll
    for (int i = 0; i < 3; ++i) {
        const int jj = j[i];
        const float dx = __fsub_rn(pos_x[jj*3+0], y0);
        const float dy = __fsub_rn(pos_x[jj*3+1], y1);
        const float dz = __fsub_rn(pos_x[jj*3+2], y2);
        const float sq = __fadd_rn(__fadd_rn(__fmul_rn(dx, dx), __fmul_rn(dy, dy)),
                                   __fmul_rn(dz, dz));
        w[i] = 1.0f / fmaxf(sq, 1e-16f);
    }
    const float inv_den = 1.0f / __fadd_rn(__fadd_rn(w[0], w[1]), w[2]);
    const float4* x4 = (const float4*)x;
    float4* o4 = (float4*)out;
    #pragma unroll
    for (int tt = 0; tt < 4; ++tt) {
        const float4 a = x4[j[0]*4 + tt];
        const float4 b = x4[j[1]*4 + tt];
        const float4 c = x4[j[2]*4 + tt];
        float4 r;
        r.x = (w[0]*a.x + w[1]*b.x + w[2]*c.x) * inv_den;
        r.y = (w[0]*a.y + w[1]*b.y + w[2]*c.y) * inv_den;
        r.z = (w[0]*a.z + w[1]*b.z + w[2]*c.z) * inv_den;
        r.w = (w[0]*a.w + w[1]*b.w + w[2]*c.w) * inv_den;
        o4[q*4 + tt] = r;
    }
}

// ========== k0: zero per-call counters (qcnt[512] + ovcnt, contiguous) ==========
__global__ __launch_bounds__(576) void zero_cnt(int* __restrict__ qcnt)
{
    if (threadIdx.x < 520) qcnt[threadIdx.x] = 0;
}

// ========== k1: block 0 builds point grid; blocks 1.. scatter queries ==========
__global__ __launch_bounds__(512) void build_scatter(
    const float* __restrict__ x,
    const float* __restrict__ pos_x, const float* __restrict__ pos_y, int ny,
    float4* __restrict__ wspt, int* __restrict__ wsidx, int* __restrict__ wcstart,
    int* __restrict__ qcnt, int* __restrict__ ovcnt,
    unsigned short* __restrict__ ovlist, unsigned short* __restrict__ qbuf,
    float* __restrict__ out)
{
    __shared__ int sA[NCELL];
    __shared__ int sB[NCELL];
    const int t = threadIdx.x;

    if (blockIdx.x == 0) {
        // ---- point grid build (byte-identical to proven r6/7/9/10 code) ----
        sA[t] = 0;
        __syncthreads();

        const float4* px4 = (const float4*)pos_x;
        const float4 v0 = px4[t*3+0], v1 = px4[t*3+1], v2 = px4[t*3+2];
        const float pxx[4] = {v0.x, v0.w, v1.z, v2.y};
        const float pyy[4] = {v0.y, v1.x, v1.w, v2.z};
        const float pzz[4] = {v0.z, v1.y, v2.x, v2.w};
        int cc[4];
        #pragma unroll
        for (int i = 0; i < 4; ++i) {
            cc[i] = (cell_of(pzz[i]) * GD + cell_of(pyy[i])) * GD + cell_of(pxx[i]);
            atomicAdd(&sA[cc[i]], 1);
        }
        __syncthreads();

        if (t < 64) {
            const int base = t * 8;
            int v[8];
            int run = 0;
            #pragma unroll
            for (int i = 0; i < 8; ++i) { run += sA[base + i]; v[i] = run; }
            int xs = run;
            #pragma unroll
            for (int off = 1; off < 64; off <<= 1) {
                const int y = __shfl_up(xs, off);
                if (t >= off) xs += y;
            }
            const int excl = xs - run;
            #pragma unroll
            for (int i = 0; i < 8; ++i) {
                const int inc = excl + v[i];
                wcstart[base + i + 1] = inc;
                sB[base + i] = inc - sA[base + i];
            }
            if (t == 0) wcstart[0] = 0;
        }
        __syncthreads();

        #pragma unroll
        for (int i = 0; i < 4; ++i) {
            const int p = t * 4 + i;
            const int pos = atomicAdd(&sB[cc[i]], 1);
            const float sx = __fadd_rn(__fadd_rn(__fmul_rn(pxx[i], pxx[i]),
                                                 __fmul_rn(pyy[i], pyy[i])),
                                       __fmul_rn(pzz[i], pzz[i]));
            wspt[pos] = make_float4(pxx[i], pyy[i], pzz[i], sx);
            wsidx[pos] = p;
        }
    } else {
        // ---- direct bucket scatter (no ordering dependence on block 0) ----
        const int q = (blockIdx.x - 1) * 512 + t;
        if (q < ny) {
            const float y0 = pos_y[q*3+0], y1 = pos_y[q*3+1], y2 = pos_y[q*3+2];
            const int c = (cell_of(y2) * GD + cell_of(y1)) * GD + cell_of(y0);
            const int pos = atomicAdd(&qcnt[c], 1);
            if (pos < CAPQ) {
                qbuf[c * CAPQ + pos] = (unsigned short)q;
            } else {
                const int op = atomicAdd(ovcnt, 1);
                if (op < OVCAP) {
                    ovlist[op] = (unsigned short)q;
                } else {
                    // ultimate fallback (never expected): inline brute over RAW
                    // pos_x (inputs only — wspt is being built concurrently),
                    // exact proven numerics; strict < keeps lowest idx on ties.
                    const float sy = __fadd_rn(__fadd_rn(__fmul_rn(y0, y0),
                                                         __fmul_rn(y1, y1)),
                                               __fmul_rn(y2, y2));
                    uint64_t b0 = ~0ull, b1 = ~0ull, b2 = ~0ull;
                    for (int p = 0; p < NXP; ++p) {
                        const float px = pos_x[p*3+0], py = pos_x[p*3+1], pz = pos_x[p*3+2];
                        const float sx = __fadd_rn(__fadd_rn(__fmul_rn(px, px),
                                                             __fmul_rn(py, py)),
                                                   __fmul_rn(pz, pz));
                        const float dot = __fmaf_rn(y2, pz,
                                          __fmaf_rn(y1, py, __fmul_rn(y0, px)));
                        const float d = __fmaf_rn(-2.0f, dot, __fadd_rn(sy, sx));
                        const uint64_t kk = ((uint64_t)mono(d) << 32) | (uint32_t)p;
                        if (kk < b2) ins_fast(kk, b0, b1, b2);
                    }
                    write_out_full(x, pos_x, out, q, y0, y1, y2, b0, b1, b2);
                }
            }
        }
    }
}

// ========== k2: cell blocks (proven r10 path) + overflow blocks ==========
__global__ __launch_bounds__(128) void knn_cell(
    const float* __restrict__ x, const float* __restrict__ pos_x,
    const float* __restrict__ pos_y,
    const float4* __restrict__ wspt, const int* __restrict__ wsidx,
    const int* __restrict__ wcst,
    const int* __restrict__ qcnt, const unsigned short* __restrict__ qbuf,
    const int* __restrict__ ovcnt, const unsigned short* __restrict__ ovlist,
    float* __restrict__ out)
{
    __shared__ float4 scand[CAP];
    __shared__ int    scidx[CAP];
    __shared__ int    rst[25], roff[26];
    __shared__ int    sL, sForce;

    const int t = threadIdx.x;
    const int wave = t >> 6, lane = t & 63;

    if (blockIdx.x >= NCELL) {
        // ---- overflow blocks: wave-coop terminal brute (proven escalation math)
        int n_ov = *ovcnt;
        n_ov = n_ov > OVCAP ? OVCAP : n_ov;
        for (int i = (blockIdx.x - NCELL) * 2 + wave; i < n_ov; i += OVB * 2) {
            const int q = (int)ovlist[i];
            const float y0 = pos_y[q*3+0], y1 = pos_y[q*3+1], y2 = pos_y[q*3+2];
            const float sy = __fadd_rn(__fadd_rn(__fmul_rn(y0, y0), __fmul_rn(y1, y1)),
                                       __fmul_rn(y2, y2));
            uint64_t m0 = ~0ull, m1 = ~0ull, m2 = ~0ull;
            for (int p = lane; p < NXP; p += 64) {
                const float4 pt = wspt[p];
                const float dot = __fmaf_rn(y2, pt.z,
                                  __fmaf_rn(y1, pt.y, __fmul_rn(y0, pt.x)));
                const float d = __fmaf_rn(-2.0f, dot, __fadd_rn(sy, pt.w));
                const uint64_t kk = ((uint64_t)mono(d) << 32) | (uint32_t)wsidx[p];
                if (kk < m2) ins_dedup(kk, m0, m1, m2);
            }
            #pragma unroll
            for (int mask = 1; mask < 64; mask <<= 1) {
                const uint64_t r0 = shfl_xor_u64(m0, mask);
                const uint64_t r1 = shfl_xor_u64(m1, mask);
                const uint64_t r2 = shfl_xor_u64(m2, mask);
                ins_dedup(r0, m0, m1, m2);
                ins_dedup(r1, m0, m1, m2);
                ins_dedup(r2, m0, m1, m2);
            }
            if (lane == 0) write_out_full(x, pos_x, out, q, y0, y1, y2, m0, m1, m2);
        }
        return;
    }

    const int c = blockIdx.x;
    const int cx = c & 7, cy = (c >> 3) & 7, cz = c >> 6;

    const int bcnt = (int)(cx == 0 || cx == GD-1) + (int)(cy == 0 || cy == GD-1)
                   + (int)(cz == 0 || cz == GD-1);
    const int R  = (bcnt >= 2) ? 2 : 1;
    const int W  = 2 * R + 1;
    const int NR = W * W;

    if (t < NR) {
        const int uz = cz + t / W - R, uy = cy + t % W - R;
        int st = 0, len = 0;
        if (((unsigned)uz < (unsigned)GD) & ((unsigned)uy < (unsigned)GD)) {
            const int xa = cx - R < 0 ? 0 : cx - R;
            const int xb = cx + R > GD - 1 ? GD - 1 : cx + R;
            const int cb = (uz * GD + uy) * GD;
            st  = wcst[cb + xa];
            len = wcst[cb + xb + 1] - st;
        }
        rst[t] = st;
        roff[t] = len;
    }
    __syncthreads();
    if (t == 0) {
        int o = 0;
        #pragma unroll 1
        for (int r = 0; r < NR; ++r) { const int l = roff[r]; roff[r] = o; o += l; }
        roff[NR] = o;
        sL = o > CAP ? CAP : o;
        sForce = (o > CAP) ? 1 : 0;
    }
    __syncthreads();

    const int L = sL, Lpad = (sL + 7) & ~7, force = sForce;
    for (int i = t; i < L; i += 128) {
        int r = 0;
        while (i >= roff[r + 1]) ++r;
        const int src = rst[r] + (i - roff[r]);
        scand[i] = wspt[src];
        scidx[i] = wsidx[src];
    }
    for (int i = L + t; i < Lpad; i += 128) {
        scand[i] = make_float4(0.f, 0.f, 0.f, 3e30f);  // sentinel
        scidx[i] = 0x7fffffff;
    }
    __syncthreads();

    int qe = qcnt[c];
    qe = qe > CAPQ ? CAPQ : qe;
    const unsigned short* myq = qbuf + c * CAPQ;

    for (int i0 = wave * 64; i0 < qe; i0 += 128) {
        const int slot = i0 + lane;
        const bool active = slot < qe;
        const int q = active ? (int)myq[slot] : 0;
        float y0 = 0.f, y1 = 0.f, y2 = 0.f;
        if (active) { y0 = pos_y[q*3+0]; y1 = pos_y[q*3+1]; y2 = pos_y[q*3+2]; }
        const float sy = __fadd_rn(__fadd_rn(__fmul_rn(y0, y0), __fmul_rn(y1, y1)),
                                   __fmul_rn(y2, y2));

        // exact clearance to staged cube (proven r9/r10)
        float clr = 1e30f;
        if (cx - R > 0)      clr = fminf(clr, y0 - (float)(cx - R) * HCELL);
        if (cx + R < GD - 1) clr = fminf(clr, (float)(cx + R + 1) * HCELL - y0);
        if (cy - R > 0)      clr = fminf(clr, y1 - (float)(cy - R) * HCELL);
        if (cy + R < GD - 1) clr = fminf(clr, (float)(cy + R + 1) * HCELL - y1);
        if (cz - R > 0)      clr = fminf(clr, y2 - (float)(cz - R) * HCELL);
        if (cz + R < GD - 1) clr = fminf(clr, (float)(cz + R + 1) * HCELL - y2);
        const float thr = clr * clr;

        uint64_t b0 = ~0ull, b1 = ~0ull, b2 = ~0ull;

        // phase A: wave-uniform broadcast scan (proven numerics)
        for (int j = 0; j < Lpad; j += 8) {
            #pragma unroll
            for (int u = 0; u < 8; ++u) {
                const float4 pt = scand[j + u];
                const int oi = scidx[j + u];
                const float dot = __fmaf_rn(y2, pt.z,
                                  __fmaf_rn(y1, pt.y, __fmul_rn(y0, pt.x)));
                const float d = __fmaf_rn(-2.0f, dot, __fadd_rn(sy, pt.w));
                const uint64_t kk = ((uint64_t)mono(d) << 32) | (uint32_t)oi;
                const bool lt0 = kk < b0, lt1 = kk < b1, lt2 = kk < b2;
                b2 = lt1 ? b1 : (lt2 ? kk : b2);
                b1 = lt0 ? b0 : (lt1 ? kk : b1);
                b0 = lt0 ? kk : b0;
            }
        }

        // escalation (proven): wave-coop terminal brute with dedup
        bool esc = false;
        if (active) {
            const bool have3 = (b2 != ~0ull);
            const float b2d = unmono((uint32_t)(b2 >> 32));
            esc = !(have3 && (b2d + 1e-4f < thr)) | (force != 0);
        }
        unsigned long long bal = __ballot(esc);
        while (bal) {
            const int e = __ffsll(bal) - 1;
            bal &= bal - 1;
            const float ey0 = __shfl(y0, e), ey1 = __shfl(y1, e), ey2 = __shfl(y2, e);
            const float esy = __shfl(sy, e);
            uint64_t m0 = shfl_u64(b0, e), m1 = shfl_u64(b1, e), m2 = shfl_u64(b2, e);
            for (int p = lane; p < NXP; p += 64) {
                const float4 pt = wspt[p];
                const float dot = __fmaf_rn(ey2, pt.z,
                                  __fmaf_rn(ey1, pt.y, __fmul_rn(ey0, pt.x)));
                const float d = __fmaf_rn(-2.0f, dot, __fadd_rn(esy, pt.w));
                const uint64_t kk = ((uint64_t)mono(d) << 32) | (uint32_t)wsidx[p];
                if (kk < m2) ins_dedup(kk, m0, m1, m2);
            }
            #pragma unroll
            for (int mask = 1; mask < 64; mask <<= 1) {
                const uint64_t r0 = shfl_xor_u64(m0, mask);
                const uint64_t r1 = shfl_xor_u64(m1, mask);
                const uint64_t r2 = shfl_xor_u64(m2, mask);
                ins_dedup(r0, m0, m1, m2);
                ins_dedup(r1, m0, m1, m2);
                ins_dedup(r2, m0, m1, m2);
            }
            if (lane == e) { b0 = m0; b1 = m1; b2 = m2; }
        }

        if (active) write_out_full(x, pos_x, out, q, y0, y1, y2, b0, b1, b2);
    }
}

// =============== fallback (round-7 kernel, 43 KB ws; proven 34 us) ===============
#define QBLK  512
#define SEG   8
#define QPB   (QBLK / SEG)
#define QGRID 512

__device__ __forceinline__ void merge_group8(uint64_t& b0, uint64_t& b1, uint64_t& b2) {
    #pragma unroll
    for (int mask = 1; mask < SEG; mask <<= 1) {
        const uint64_t r0 = shfl_xor_u64(b0, mask);
        const uint64_t r1 = shfl_xor_u64(b1, mask);
        const uint64_t r2 = shfl_xor_u64(b2, mask);
        ins_dedup(r0, b0, b1, b2);
        ins_dedup(r1, b0, b1, b2);
        ins_dedup(r2, b0, b1, b2);
    }
}

__global__ __launch_bounds__(QBLK) void knn_query_fb(
    const float* __restrict__ x, const float* __restrict__ pos_x,
    const float* __restrict__ pos_y,
    const float4* __restrict__ wspt, const int* __restrict__ wsidx,
    const int* __restrict__ wcstart,
    float* __restrict__ out, int ny)
{
    __shared__ float4 spt[NXP];
    __shared__ int    sidx[NXP];
    __shared__ int    cstart[NCELL + 1];

    const int t = threadIdx.x;
    for (int i = t; i < NXP; i += QBLK) spt[i] = wspt[i];
    for (int i = t; i < NXP; i += QBLK) sidx[i] = wsidx[i];
    for (int i = t; i < NCELL + 1; i += QBLK) cstart[i] = wcstart[i];
    __syncthreads();

    const int s = t & (SEG - 1);
    const int nbatch = (ny + QPB - 1) / QPB;

    for (int batch = blockIdx.x; batch < nbatch; batch += gridDim.x) {
        const int q = batch * QPB + (t >> 3);
        if (q >= ny) continue;

        const float y0 = pos_y[q*3+0], y1 = pos_y[q*3+1], y2 = pos_y[q*3+2];
        const float sy = __fadd_rn(__fadd_rn(__fmul_rn(y0, y0), __fmul_rn(y1, y1)),
                                   __fmul_rn(y2, y2));
        const int cx = cell_of(y0), cy = cell_of(y1), cz = cell_of(y2);

        uint64_t b0 = ~0ull, b1 = ~0ull, b2 = ~0ull;

#define EVAL_BODY(P, INS)                                                       \
        {                                                                       \
            const float4 pt = spt[P];                                           \
            const float dot = __fmaf_rn(y2, pt.z,                               \
                              __fmaf_rn(y1, pt.y, __fmul_rn(y0, pt.x)));        \
            const float d = __fmaf_rn(-2.0f, dot, __fadd_rn(sy, pt.w));         \
            const uint64_t kk = ((uint64_t)mono(d) << 32) | (uint32_t)sidx[P];  \
            if (kk < b2) INS(kk, b0, b1, b2);                                   \
        }

        const int x0 = cx - 1 < 0 ? 0 : cx - 1;
        const int x1 = cx + 1 > GD - 1 ? GD - 1 : cx + 1;
        #pragma unroll
        for (int r = 0; r < 9; ++r) {
            const int uz = cz + r / 3 - 1, uy = cy + r % 3 - 1;
            int st = 0, en = 0;
            if (((unsigned)uz < (unsigned)GD) & ((unsigned)uy < (unsigned)GD)) {
                const int cb = (uz * GD + uy) * GD;
                st = cstart[cb + x0];
                en = cstart[cb + x1 + 1];
            }
            for (int p = st + s; p < en; p += SEG) EVAL_BODY(p, ins_fast)
        }
        merge_group8(b0, b1, b2);

        {
            bool have3 = (b2 != ~0ull);
            float b2d = unmono((uint32_t)(b2 >> 32));
            if (!(have3 && (b2d + 1e-4f < 0.015625f))) {
                for (int r = 0; r < 25; ++r) {
                    const int dzi = r / 5 - 2, dyi = r % 5 - 2;
                    const int uz = cz + dzi, uy = cy + dyi;
                    if (((unsigned)uz >= (unsigned)GD) | ((unsigned)uy >= (unsigned)GD))
                        continue;
                    const int cb = (uz * GD + uy) * GD;
                    if (dzi == -2 || dzi == 2 || dyi == -2 || dyi == 2) {
                        const int xa = cx - 2 < 0 ? 0 : cx - 2;
                        const int xb = cx + 2 > GD - 1 ? GD - 1 : cx + 2;
                        const int st = cstart[cb + xa], en = cstart[cb + xb + 1];
                        for (int p = st + s; p < en; p += SEG) EVAL_BODY(p, ins_fast)
                    } else {
                        if (cx - 2 >= 0) {
                            const int st = cstart[cb + cx - 2], en = cstart[cb + cx - 1];
                            for (int p = st + s; p < en; p += SEG) EVAL_BODY(p, ins_fast)
                        }
                        if (cx + 2 <= GD - 1) {
                            const int st = cstart[cb + cx + 2], en = cstart[cb + cx + 3];
                            for (int p = st + s; p < en; p += SEG) EVAL_BODY(p, ins_fast)
                        }
                    }
                }
                merge_group8(b0, b1, b2);

                have3 = (b2 != ~0ull);
                b2d = unmono((uint32_t)(b2 >> 32));
                if (!(have3 && (b2d + 1e-4f < 0.0625f))) {
                    for (int p = s; p < NXP; p += SEG) EVAL_BODY(p, ins_dedup)
                    merge_group8(b0, b1, b2);
                }
            }
        }
#undef EVAL_BODY

        const int j[3] = { (int)(uint32_t)b0, (int)(uint32_t)b1, (int)(uint32_t)b2 };
        float w[3];
        #pragma unroll
        for (int i = 0; i < 3; ++i) {
            const int jj = j[i];
            const float dx = __fsub_rn(pos_x[jj*3+0], y0);
            const float dy = __fsub_rn(pos_x[jj*3+1], y1);
            const float dz = __fsub_rn(pos_x[jj*3+2], y2);
            const float sq = __fadd_rn(__fadd_rn(__fmul_rn(dx, dx), __fmul_rn(dy, dy)),
                                       __fmul_rn(dz, dz));
            w[i] = 1.0f / fmaxf(sq, 1e-16f);
        }
        const float inv_den = 1.0f / __fadd_rn(__fadd_rn(w[0], w[1]), w[2]);

        const float2* x2 = (const float2*)x;
        float2* o2 = (float2*)out;
        const float2 a = x2[j[0]*8 + s];
        const float2 b = x2[j[1]*8 + s];
        const float2 c = x2[j[2]*8 + s];
        float2 rr;
        rr.x = (w[0]*a.x + w[1]*b.x + w[2]*c.x) * inv_den;
        rr.y = (w[0]*a.y + w[1]*b.y + w[2]*c.y) * inv_den;
        o2[q*8 + s] = rr;
    }
}

extern "C" void kernel_launch(void* const* d_in, const int* in_sizes, int n_in,
                              void* d_out, int out_size, void* d_ws, size_t ws_size,
                              hipStream_t stream) {
    const float* x     = (const float*)d_in[0];  // [2048, 16]
    const float* pos_x = (const float*)d_in[1];  // [2048, 3]
    const float* pos_y = (const float*)d_in[2];  // [65536, 3]
    float* out = (float*)d_out;
    const int ny = in_sizes[2] / 3;  // 65536

    float4*         wspt  = (float4*)        ((char*)d_ws + WS_SPT);
    int*            wsidx = (int*)           ((char*)d_ws + WS_SIDX);
    int*            wcst  = (int*)           ((char*)d_ws + WS_CST);
    int*            qcnt  = (int*)           ((char*)d_ws + WS_QCNT);
    int*            ovcnt = (int*)           ((char*)d_ws + WS_OVCNT);
    unsigned short* ovl   = (unsigned short*)((char*)d_ws + WS_OVL);
    unsigned short* qbuf  = (unsigned short*)((char*)d_ws + WS_QBUF);

    const int nqb = (ny + 511) / 512;

    if (ws_size >= (size_t)WS_NEED && ny <= 65536) {
        zero_cnt<<<1, 576, 0, stream>>>(qcnt);
        build_scatter<<<1 + nqb, 512, 0, stream>>>(x, pos_x, pos_y, ny,
                                                   wspt, wsidx, wcst,
                                                   qcnt, ovcnt, ovl, qbuf, out);
        knn_cell<<<NCELL + OVB, 128, 0, stream>>>(x, pos_x, pos_y,
                                                  wspt, wsidx, wcst,
                                                  qcnt, qbuf, ovcnt, ovl, out);
    } else {
        build_scatter<<<1, 512, 0, stream>>>(x, pos_x, pos_y, 0,
                                             wspt, wsidx, wcst,
                                             qcnt, ovcnt, ovl, qbuf, out);
        knn_query_fb<<<QGRID, QBLK, 0, stream>>>(x, pos_x, pos_y, wspt, wsidx, wcst,
                                                 out, ny);
    }
}

// Round 12
// 54.645 us; speedup vs baseline: 1.7405x; 1.0871x over previous
//
#include <hip/hip_runtime.h>
#include <stdint.h>

#define NXP   2048   // pivotal (source) nodes
#define NC    16     // feature channels
#define GD    8      // grid cells per axis
#define NCELL (GD*GD*GD)   // 512
#define CAP   512    // max staged candidates per cell block
#define QCAP  512    // query LDS list capacity per pass
#define HCELL 0.125f
#define NQB   128    // query scatter blocks
#define BQ    512    // queries per scatter block

// ---- d_ws layout (bytes); total 305472 <= 312832 (proven available, r9) ----
#define WS_SPT   0        // float4[2048]
#define WS_SIDX  32768    // int[2048]
#define WS_CST   40960    // int[513]                     (ends 43012)
#define WS_SCN   43072    // u16[128][513] per-block cell scan (ends 174400)
#define WS_QSRT  174400   // u16[65536] block-sorted query ids (ends 305472)
#define WS_NEED  305472

__device__ __forceinline__ int cell_of(float v) {
    int c = (int)(v * (float)GD);
    c = c > GD - 1 ? GD - 1 : c;
    return c < 0 ? 0 : c;
}
__device__ __forceinline__ uint32_t mono(float d) {
    uint32_t b = __float_as_uint(d);
    return b ^ (uint32_t)(((int32_t)b >> 31) | 0x80000000);
}
__device__ __forceinline__ float unmono(uint32_t m) {
    uint32_t b = (m & 0x80000000u) ? (m ^ 0x80000000u) : ~m;
    return __uint_as_float(b);
}
__device__ __forceinline__ void ins_fast(uint64_t k, uint64_t& b0, uint64_t& b1, uint64_t& b2) {
    const bool lt0 = k < b0, lt1 = k < b1;
    b2 = lt1 ? b1 : k;
    b1 = lt0 ? b0 : (lt1 ? k : b1);
    b0 = lt0 ? k  : b0;
}
__device__ __forceinline__ void ins_dedup(uint64_t k, uint64_t& b0, uint64_t& b1, uint64_t& b2) {
    if (k == b0 || k == b1 || k == b2) return;
    const bool lt0 = k < b0, lt1 = k < b1, lt2 = k < b2;
    b2 = lt1 ? b1 : (lt2 ? k : b2);
    b1 = lt0 ? b0 : (lt1 ? k : b1);
    b0 = lt0 ? k  : b0;
}
__device__ __forceinline__ uint64_t shfl_u64(uint64_t v, int src) {
    const int lo = __shfl((int)(uint32_t)v, src);
    const int hi = __shfl((int)(uint32_t)(v >> 32), src);
    return ((uint64_t)(uint32_t)hi << 32) | (uint32_t)lo;
}
__device__ __forceinline__ uint64_t shfl_xor_u64(uint64_t v, int mask) {
    const int lo = __shfl_xor((int)(uint32_t)v, mask);
    const int hi = __shfl_xor((int)(uint32_t)(v >> 32), mask);
    return ((uint64_t)(uint32_t)hi << 32) | (uint32_t)lo;
}

// shared epilogue: exact-diff weights (reference numerics) + 16-channel write
__device__ __forceinline__ void write_out_full(
    const float* __restrict__ x, const float* __restrict__ pos_x,
    float* __restrict__ out, int q, float y0, float y1, float y2,
    uint64_t b0, uint64_t b1, uint64_t b2)
{
    const int j[3] = { (int)(uint32_t)b0, (int)(uint32_t)b1, (int)(uint32_t)b2 };
    float w[3];
    #pragma unroll
    for (int i = 0; i < 3; ++i) {
        const int jj = j[i];
        const float dx = __fsub_rn(pos_x[jj*3+0], y0);
        const float dy = __fsub_rn(pos_x[jj*3+1], y1);
        const float dz = __fsub_rn(pos_x[jj*3+2], y2);
        const float sq = __fadd_rn(__fadd_rn(__fmul_rn(dx, dx), __fmul_rn(dy, dy)),
                                   __fmul_rn(dz, dz));
        w[i] = 1.0f / fmaxf(sq, 1e-16f);
    }
    const float inv_den = 1.0f / __fadd_rn(__fadd_rn(w[0], w[1]), w[2]);
    const float4* x4 = (const float4*)x;
    float4* o4 = (float4*)out;
    #pragma unroll
    for (int tt = 0; tt < 4; ++tt) {
        const float4 a = x4[j[0]*4 + tt];
        const float4 b = x4[j[1]*4 + tt];
        const float4 c = x4[j[2]*4 + tt];
        float4 r;
        r.x = (w[0]*a.x + w[1]*b.x + w[2]*c.x) * inv_den;
        r.y = (w[0]*a.y + w[1]*b.y + w[2]*c.y) * inv_den;
        r.z = (w[0]*a.z + w[1]*b.z + w[2]*c.z) * inv_den;
        r.w = (w[0]*a.w + w[1]*b.w + w[2]*c.w) * inv_den;
        o4[q*4 + tt] = r;
    }
}

// ========== K1: block 0 builds point grid; blocks 1..128 LDS-sort queries ==========
__global__ __launch_bounds__(512) void build_scatter(
    const float* __restrict__ pos_x, const float* __restrict__ pos_y, int ny,
    float4* __restrict__ wspt, int* __restrict__ wsidx, int* __restrict__ wcstart,
    unsigned short* __restrict__ scan2d, unsigned short* __restrict__ qsrt)
{
    __shared__ int sA[NCELL];
    __shared__ int sB[NCELL];
    const int t = threadIdx.x;

    if (blockIdx.x == 0) {
        // ---- point grid build (byte-identical to proven r6..r11 code) ----
        sA[t] = 0;
        __syncthreads();

        const float4* px4 = (const float4*)pos_x;
        const float4 v0 = px4[t*3+0], v1 = px4[t*3+1], v2 = px4[t*3+2];
        const float pxx[4] = {v0.x, v0.w, v1.z, v2.y};
        const float pyy[4] = {v0.y, v1.x, v1.w, v2.z};
        const float pzz[4] = {v0.z, v1.y, v2.x, v2.w};
        int cc[4];
        #pragma unroll
        for (int i = 0; i < 4; ++i) {
            cc[i] = (cell_of(pzz[i]) * GD + cell_of(pyy[i])) * GD + cell_of(pxx[i]);
            atomicAdd(&sA[cc[i]], 1);
        }
        __syncthreads();

        if (t < 64) {
            const int base = t * 8;
            int v[8];
            int run = 0;
            #pragma unroll
            for (int i = 0; i < 8; ++i) { run += sA[base + i]; v[i] = run; }
            int xs = run;
            #pragma unroll
            for (int off = 1; off < 64; off <<= 1) {
                const int y = __shfl_up(xs, off);
                if (t >= off) xs += y;
            }
            const int excl = xs - run;
            #pragma unroll
            for (int i = 0; i < 8; ++i) {
                const int inc = excl + v[i];
                wcstart[base + i + 1] = inc;
                sB[base + i] = inc - sA[base + i];
            }
            if (t == 0) wcstart[0] = 0;
        }
        __syncthreads();

        #pragma unroll
        for (int i = 0; i < 4; ++i) {
            const int p = t * 4 + i;
            const int pos = atomicAdd(&sB[cc[i]], 1);
            const float sx = __fadd_rn(__fadd_rn(__fmul_rn(pxx[i], pxx[i]),
                                                 __fmul_rn(pyy[i], pyy[i])),
                                       __fmul_rn(pzz[i], pzz[i]));
            wspt[pos] = make_float4(pxx[i], pyy[i], pzz[i], sx);
            wsidx[pos] = p;
        }
    } else {
        // ---- LDS counting sort of this block's 512 queries (no global atomics) ----
        const int b = blockIdx.x - 1;
        sA[t] = 0;
        __syncthreads();

        const int q = b * BQ + t;
        int c = -1;
        if (q < ny) {
            c = (cell_of(pos_y[q*3+2]) * GD + cell_of(pos_y[q*3+1])) * GD
              + cell_of(pos_y[q*3+0]);
            atomicAdd(&sA[c], 1);     // LDS atomic
        }
        __syncthreads();

        // exclusive scan of 512 counts (wave 0, proven pattern)
        if (t < 64) {
            const int base = t * 8;
            int v[8];
            int run = 0;
            #pragma unroll
            for (int i = 0; i < 8; ++i) { run += sA[base + i]; v[i] = run; }
            int xs = run;
            #pragma unroll
            for (int off = 1; off < 64; off <<= 1) {
                const int y = __shfl_up(xs, off);
                if (t >= off) xs += y;
            }
            const int excl = xs - run;
            #pragma unroll
            for (int i = 0; i < 8; ++i)
                sB[base + i] = excl + v[i] - sA[base + i];   // exclusive start
        }
        __syncthreads();

        // write the scan row (coalesced u16 stores); row fully rewritten per call
        scan2d[b * 513 + t] = (unsigned short)sB[t];
        if (t == 0) {
            int nb = ny - b * BQ;
            nb = nb < 0 ? 0 : (nb > BQ ? BQ : nb);
            scan2d[b * 513 + 512] = (unsigned short)nb;
        }
        __syncthreads();   // scan row read from sB must complete before cursors move

        if (q < ny) {
            const int pos = atomicAdd(&sB[c], 1);   // LDS atomic rank
            qsrt[b * BQ + pos] = (unsigned short)q;
        }
    }
}

// ========== K2: one block per cell; gather queries from segment table ==========
__global__ __launch_bounds__(128) void knn_cell(
    const float* __restrict__ x, const float* __restrict__ pos_x,
    const float* __restrict__ pos_y,
    const float4* __restrict__ wspt, const int* __restrict__ wsidx,
    const int* __restrict__ wcst,
    const unsigned short* __restrict__ scan2d, const unsigned short* __restrict__ qsrt,
    float* __restrict__ out)
{
    __shared__ float4 scand[CAP];
    __shared__ int    scidx[CAP];
    __shared__ int    rst[25], roff[26];
    __shared__ int    sL, sForce;
    __shared__ unsigned short qlist[QCAP];
    __shared__ int    wsum[2];

    const int t = threadIdx.x;
    const int c = blockIdx.x;
    const int cx = c & 7, cy = (c >> 3) & 7, cz = c >> 6;
    const int wave = t >> 6, lane = t & 63;

    // R=2 for ANY boundary cell (kills face-cell escalation tail); R=1 interior
    const int bcnt = (int)(cx == 0 || cx == GD-1) + (int)(cy == 0 || cy == GD-1)
                   + (int)(cz == 0 || cz == GD-1);
    const int R  = (bcnt >= 1) ? 2 : 1;
    const int W  = 2 * R + 1;
    const int NR = W * W;

    if (t < NR) {
        const int uz = cz + t / W - R, uy = cy + t % W - R;
        int st = 0, len = 0;
        if (((unsigned)uz < (unsigned)GD) & ((unsigned)uy < (unsigned)GD)) {
            const int xa = cx - R < 0 ? 0 : cx - R;
            const int xb = cx + R > GD - 1 ? GD - 1 : cx + R;
            const int cb = (uz * GD + uy) * GD;
            st  = wcst[cb + xa];
            len = wcst[cb + xb + 1] - st;
        }
        rst[t] = st;
        roff[t] = len;
    }
    __syncthreads();
    if (t == 0) {
        int o = 0;
        #pragma unroll 1
        for (int r = 0; r < NR; ++r) { const int l = roff[r]; roff[r] = o; o += l; }
        roff[NR] = o;
        sL = o > CAP ? CAP : o;
        sForce = (o > CAP) ? 1 : 0;
    }
    __syncthreads();

    const int L = sL, Lpad = (sL + 7) & ~7, force = sForce;
    for (int i = t; i < L; i += 128) {
        int r = 0;
        while (i >= roff[r + 1]) ++r;
        const int src = rst[r] + (i - roff[r]);
        scand[i] = wspt[src];
        scidx[i] = wsidx[src];
    }
    for (int i = L + t; i < Lpad; i += 128) {
        scand[i] = make_float4(0.f, 0.f, 0.f, 3e30f);  // sentinel
        scidx[i] = 0x7fffffff;
    }

    // ---- query gather: lane t = source block t; segment [s0, s0+cnt) ----
    const int s0  = (int)scan2d[t * 513 + c];
    const int cnt = (int)scan2d[t * 513 + c + 1] - s0;
    int inc = cnt;
    #pragma unroll
    for (int off = 1; off < 64; off <<= 1) {
        const int y = __shfl_up(inc, off);
        if (lane >= off) inc += y;
    }
    if (lane == 63) wsum[wave] = inc;
    __syncthreads();
    const int base  = inc - cnt + (wave ? wsum[0] : 0);
    const int total = wsum[0] + wsum[1];

    for (int S = 0; S < total; S += QCAP) {
        __syncthreads();
        for (int k = 0; k < cnt; ++k) {
            const int g = base + k;
            if (g >= S && g < S + QCAP) qlist[g - S] = qsrt[t * BQ + s0 + k];
        }
        __syncthreads();
        const int n = (total - S) < QCAP ? (total - S) : QCAP;

        for (int i0 = wave * 64; i0 < n; i0 += 128) {
            const int slot = i0 + lane;
            const bool active = slot < n;
            const int q = active ? (int)qlist[slot] : 0;
            float y0 = 0.f, y1 = 0.f, y2 = 0.f;
            if (active) { y0 = pos_y[q*3+0]; y1 = pos_y[q*3+1]; y2 = pos_y[q*3+2]; }
            const float sy = __fadd_rn(__fadd_rn(__fmul_rn(y0, y0), __fmul_rn(y1, y1)),
                                       __fmul_rn(y2, y2));

            // exact clearance to staged cube (proven r9/r10/r11)
            float clr = 1e30f;
            if (cx - R > 0)      clr = fminf(clr, y0 - (float)(cx - R) * HCELL);
            if (cx + R < GD - 1) clr = fminf(clr, (float)(cx + R + 1) * HCELL - y0);
            if (cy - R > 0)      clr = fminf(clr, y1 - (float)(cy - R) * HCELL);
            if (cy + R < GD - 1) clr = fminf(clr, (float)(cy + R + 1) * HCELL - y1);
            if (cz - R > 0)      clr = fminf(clr, y2 - (float)(cz - R) * HCELL);
            if (cz + R < GD - 1) clr = fminf(clr, (float)(cz + R + 1) * HCELL - y2);
            const float thr = clr * clr;

            uint64_t b0 = ~0ull, b1 = ~0ull, b2 = ~0ull;

            // phase A: wave-uniform broadcast scan (proven numerics)
            for (int j = 0; j < Lpad; j += 8) {
                #pragma unroll
                for (int u = 0; u < 8; ++u) {
                    const float4 pt = scand[j + u];
                    const int oi = scidx[j + u];
                    const float dot = __fmaf_rn(y2, pt.z,
                                      __fmaf_rn(y1, pt.y, __fmul_rn(y0, pt.x)));
                    const float d = __fmaf_rn(-2.0f, dot, __fadd_rn(sy, pt.w));
                    const uint64_t kk = ((uint64_t)mono(d) << 32) | (uint32_t)oi;
                    const bool lt0 = kk < b0, lt1 = kk < b1, lt2 = kk < b2;
                    b2 = lt1 ? b1 : (lt2 ? kk : b2);
                    b1 = lt0 ? b0 : (lt1 ? kk : b1);
                    b0 = lt0 ? kk : b0;
                }
            }

            // escalation (proven): wave-coop terminal brute with dedup
            bool esc = false;
            if (active) {
                const bool have3 = (b2 != ~0ull);
                const float b2d = unmono((uint32_t)(b2 >> 32));
                esc = !(have3 && (b2d + 1e-4f < thr)) | (force != 0);
            }
            unsigned long long bal = __ballot(esc);
            while (bal) {
                const int e = __ffsll(bal) - 1;
                bal &= bal - 1;
                const float ey0 = __shfl(y0, e), ey1 = __shfl(y1, e), ey2 = __shfl(y2, e);
                const float esy = __shfl(sy, e);
                uint64_t m0 = shfl_u64(b0, e), m1 = shfl_u64(b1, e), m2 = shfl_u64(b2, e);
                for (int p = lane; p < NXP; p += 64) {
                    const float4 pt = wspt[p];
                    const float dot = __fmaf_rn(ey2, pt.z,
                                      __fmaf_rn(ey1, pt.y, __fmul_rn(ey0, pt.x)));
                    const float d = __fmaf_rn(-2.0f, dot, __fadd_rn(esy, pt.w));
                    const uint64_t kk = ((uint64_t)mono(d) << 32) | (uint32_t)wsidx[p];
                    if (kk < m2) ins_dedup(kk, m0, m1, m2);
                }
                #pragma unroll
                for (int mask = 1; mask < 64; mask <<= 1) {
                    const uint64_t r0 = shfl_xor_u64(m0, mask);
                    const uint64_t r1 = shfl_xor_u64(m1, mask);
                    const uint64_t r2 = shfl_xor_u64(m2, mask);
                    ins_dedup(r0, m0, m1, m2);
                    ins_dedup(r1, m0, m1, m2);
                    ins_dedup(r2, m0, m1, m2);
                }
                if (lane == e) { b0 = m0; b1 = m1; b2 = m2; }
            }

            if (active) write_out_full(x, pos_x, out, q, y0, y1, y2, b0, b1, b2);
        }
    }
}

// =============== fallback (round-7 kernel, 43 KB ws; proven 34 us) ===============
#define QBLK  512
#define SEG   8
#define QPB   (QBLK / SEG)
#define QGRID 512

__device__ __forceinline__ void merge_group8(uint64_t& b0, uint64_t& b1, uint64_t& b2) {
    #pragma unroll
    for (int mask = 1; mask < SEG; mask <<= 1) {
        const uint64_t r0 = shfl_xor_u64(b0, mask);
        const uint64_t r1 = shfl_xor_u64(b1, mask);
        const uint64_t r2 = shfl_xor_u64(b2, mask);
        ins_dedup(r0, b0, b1, b2);
        ins_dedup(r1, b0, b1, b2);
        ins_dedup(r2, b0, b1, b2);
    }
}

__global__ __launch_bounds__(QBLK) void knn_query_fb(
    const float* __restrict__ x, const float* __restrict__ pos_x,
    const float* __restrict__ pos_y,
    const float4* __restrict__ wspt, const int* __restrict__ wsidx,
    const int* __restrict__ wcstart,
    float* __restrict__ out, int ny)
{
    __shared__ float4 spt[NXP];
    __shared__ int    sidx[NXP];
    __shared__ int    cstart[NCELL + 1];

    const int t = threadIdx.x;
    for (int i = t; i < NXP; i += QBLK) spt[i] = wspt[i];
    for (int i = t; i < NXP; i += QBLK) sidx[i] = wsidx[i];
    for (int i = t; i < NCELL + 1; i += QBLK) cstart[i] = wcstart[i];
    __syncthreads();

    const int s = t & (SEG - 1);
    const int nbatch = (ny + QPB - 1) / QPB;

    for (int batch = blockIdx.x; batch < nbatch; batch += gridDim.x) {
        const int q = batch * QPB + (t >> 3);
        if (q >= ny) continue;

        const float y0 = pos_y[q*3+0], y1 = pos_y[q*3+1], y2 = pos_y[q*3+2];
        const float sy = __fadd_rn(__fadd_rn(__fmul_rn(y0, y0), __fmul_rn(y1, y1)),
                                   __fmul_rn(y2, y2));
        const int cx = cell_of(y0), cy = cell_of(y1), cz = cell_of(y2);

        uint64_t b0 = ~0ull, b1 = ~0ull, b2 = ~0ull;

#define EVAL_BODY(P, INS)                                                       \
        {                                                                       \
            const float4 pt = spt[P];                                           \
            const float dot = __fmaf_rn(y2, pt.z,                               \
                              __fmaf_rn(y1, pt.y, __fmul_rn(y0, pt.x)));        \
            const float d = __fmaf_rn(-2.0f, dot, __fadd_rn(sy, pt.w));         \
            const uint64_t kk = ((uint64_t)mono(d) << 32) | (uint32_t)sidx[P];  \
            if (kk < b2) INS(kk, b0, b1, b2);                                   \
        }

        const int x0 = cx - 1 < 0 ? 0 : cx - 1;
        const int x1 = cx + 1 > GD - 1 ? GD - 1 : cx + 1;
        #pragma unroll
        for (int r = 0; r < 9; ++r) {
            const int uz = cz + r / 3 - 1, uy = cy + r % 3 - 1;
            int st = 0, en = 0;
            if (((unsigned)uz < (unsigned)GD) & ((unsigned)uy < (unsigned)GD)) {
                const int cb = (uz * GD + uy) * GD;
                st = cstart[cb + x0];
                en = cstart[cb + x1 + 1];
            }
            for (int p = st + s; p < en; p += SEG) EVAL_BODY(p, ins_fast)
        }
        merge_group8(b0, b1, b2);

        {
            bool have3 = (b2 != ~0ull);
            float b2d = unmono((uint32_t)(b2 >> 32));
            if (!(have3 && (b2d + 1e-4f < 0.015625f))) {
                for (int r = 0; r < 25; ++r) {
                    const int dzi = r / 5 - 2, dyi = r % 5 - 2;
                    const int uz = cz + dzi, uy = cy + dyi;
                    if (((unsigned)uz >= (unsigned)GD) | ((unsigned)uy >= (unsigned)GD))
                        continue;
                    const int cb = (uz * GD + uy) * GD;
                    if (dzi == -2 || dzi == 2 || dyi == -2 || dyi == 2) {
                        const int xa = cx - 2 < 0 ? 0 : cx - 2;
                        const int xb = cx + 2 > GD - 1 ? GD - 1 : cx + 2;
                        const int st = cstart[cb + xa], en = cstart[cb + xb + 1];
                        for (int p = st + s; p < en; p += SEG) EVAL_BODY(p, ins_fast)
                    } else {
                        if (cx - 2 >= 0) {
                            const int st = cstart[cb + cx - 2], en = cstart[cb + cx - 1];
                            for (int p = st + s; p < en; p += SEG) EVAL_BODY(p, ins_fast)
                        }
                        if (cx + 2 <= GD - 1) {
                            const int st = cstart[cb + cx + 2], en = cstart[cb + cx + 3];
                            for (int p = st + s; p < en; p += SEG) EVAL_BODY(p, ins_fast)
                        }
                    }
                }
                merge_group8(b0, b1, b2);

                have3 = (b2 != ~0ull);
                b2d = unmono((uint32_t)(b2 >> 32));
                if (!(have3 && (b2d + 1e-4f < 0.0625f))) {
                    for (int p = s; p < NXP; p += SEG) EVAL_BODY(p, ins_dedup)
                    merge_group8(b0, b1, b2);
                }
            }
        }
#undef EVAL_BODY

        const int j[3] = { (int)(uint32_t)b0, (int)(uint32_t)b1, (int)(uint32_t)b2 };
        float w[3];
        #pragma unroll
        for (int i = 0; i < 3; ++i) {
            const int jj = j[i];
            const float dx = __fsub_rn(pos_x[jj*3+0], y0);
            const float dy = __fsub_rn(pos_x[jj*3+1], y1);
            const float dz = __fsub_rn(pos_x[jj*3+2], y2);
            const float sq = __fadd_rn(__fadd_rn(__fmul_rn(dx, dx), __fmul_rn(dy, dy)),
                                       __fmul_rn(dz, dz));
            w[i] = 1.0f / fmaxf(sq, 1e-16f);
        }
        const float inv_den = 1.0f / __fadd_rn(__fadd_rn(w[0], w[1]), w[2]);

        const float2* x2 = (const float2*)x;
        float2* o2 = (float2*)out;
        const float2 a = x2[j[0]*8 + s];
        const float2 b = x2[j[1]*8 + s];
        const float2 c = x2[j[2]*8 + s];
        float2 rr;
        rr.x = (w[0]*a.x + w[1]*b.x + w[2]*c.x) * inv_den;
        rr.y = (w[0]*a.y + w[1]*b.y + w[2]*c.y) * inv_den;
        o2[q*8 + s] = rr;
    }
}

extern "C" void kernel_launch(void* const* d_in, const int* in_sizes, int n_in,
                              void* d_out, int out_size, void* d_ws, size_t ws_size,
                              hipStream_t stream) {
    const float* x     = (const float*)d_in[0];  // [2048, 16]
    const float* pos_x = (const float*)d_in[1];  // [2048, 3]
    const float* pos_y = (const float*)d_in[2];  // [65536, 3]
    float* out = (float*)d_out;
    const int ny = in_sizes[2] / 3;  // 65536

    float4*         wspt   = (float4*)        ((char*)d_ws + WS_SPT);
    int*            wsidx  = (int*)           ((char*)d_ws + WS_SIDX);
    int*            wcst   = (int*)           ((char*)d_ws + WS_CST);
    unsigned short* scan2d = (unsigned short*)((char*)d_ws + WS_SCN);
    unsigned short* qsrt   = (unsigned short*)((char*)d_ws + WS_QSRT);

    if (ws_size >= (size_t)WS_NEED && ny <= NQB * BQ) {
        // K1: always 1+NQB blocks so every scan2d row is rewritten each call
        build_scatter<<<1 + NQB, 512, 0, stream>>>(pos_x, pos_y, ny,
                                                   wspt, wsidx, wcst, scan2d, qsrt);
        knn_cell<<<NCELL, 128, 0, stream>>>(x, pos_x, pos_y, wspt, wsidx, wcst,
                                            scan2d, qsrt, out);
    } else {
        build_scatter<<<1, 512, 0, stream>>>(pos_x, pos_y, 0,
                                             wspt, wsidx, wcst, scan2d, qsrt);
        knn_query_fb<<<QGRID, QBLK, 0, stream>>>(x, pos_x, pos_y, wspt, wsidx, wcst,
                                                 out, ny);
    }
}

// Round 14
// 40.182 us; speedup vs baseline: 2.3670x; 1.3599x over previous
//
#include <hip/hip_runtime.h>
#include <stdint.h>

#define NXP   2048   // pivotal (source) nodes
#define NC    16     // feature channels
#define GD    8      // grid cells per axis
#define NCELL (GD*GD*GD)   // 512
#define CAP   512    // max staged candidates per cell block
#define QCAP  512    // query LDS list capacity per pass
#define HCELL 0.125f
#define NQB   128    // query scatter blocks
#define BQ    512    // queries per scatter block

// ---- d_ws layout (bytes); total 305472 <= 312832 (proven available, r9) ----
#define WS_SPT   0        // float4[2048]
#define WS_SIDX  32768    // int[2048]
#define WS_CST   40960    // int[513]                     (ends 43012)
#define WS_SCN   43072    // u16[128][513] per-block cell scan (ends 174400)
#define WS_QSRT  174400   // u16[65536] block-sorted query ids (ends 305472)
#define WS_NEED  305472

__device__ __forceinline__ int cell_of(float v) {
    int c = (int)(v * (float)GD);
    c = c > GD - 1 ? GD - 1 : c;
    return c < 0 ? 0 : c;
}
__device__ __forceinline__ uint32_t mono(float d) {
    uint32_t b = __float_as_uint(d);
    return b ^ (uint32_t)(((int32_t)b >> 31) | 0x80000000);
}
__device__ __forceinline__ float unmono(uint32_t m) {
    uint32_t b = (m & 0x80000000u) ? (m ^ 0x80000000u) : ~m;
    return __uint_as_float(b);
}
__device__ __forceinline__ void ins_fast(uint64_t k, uint64_t& b0, uint64_t& b1, uint64_t& b2) {
    const bool lt0 = k < b0, lt1 = k < b1;
    b2 = lt1 ? b1 : k;
    b1 = lt0 ? b0 : (lt1 ? k : b1);
    b0 = lt0 ? k  : b0;
}
__device__ __forceinline__ void ins_dedup(uint64_t k, uint64_t& b0, uint64_t& b1, uint64_t& b2) {
    if (k == b0 || k == b1 || k == b2) return;
    const bool lt0 = k < b0, lt1 = k < b1, lt2 = k < b2;
    b2 = lt1 ? b1 : (lt2 ? k : b2);
    b1 = lt0 ? b0 : (lt1 ? k : b1);
    b0 = lt0 ? k  : b0;
}
__device__ __forceinline__ uint64_t shfl_u64(uint64_t v, int src) {
    const int lo = __shfl((int)(uint32_t)v, src);
    const int hi = __shfl((int)(uint32_t)(v >> 32), src);
    return ((uint64_t)(uint32_t)hi << 32) | (uint32_t)lo;
}
__device__ __forceinline__ uint64_t shfl_xor_u64(uint64_t v, int mask) {
    const int lo = __shfl_xor((int)(uint32_t)v, mask);
    const int hi = __shfl_xor((int)(uint32_t)(v >> 32), mask);
    return ((uint64_t)(uint32_t)hi << 32) | (uint32_t)lo;
}

// shared epilogue: exact-diff weights (reference numerics) + 16-channel write
__device__ __forceinline__ void write_out_full(
    const float* __restrict__ x, const float* __restrict__ pos_x,
    float* __restrict__ out, int q, float y0, float y1, float y2,
    uint64_t b0, uint64_t b1, uint64_t b2)
{
    const int j[3] = { (int)(uint32_t)b0, (int)(uint32_t)b1, (int)(uint32_t)b2 };
    float w[3];
    #pragma unroll
    for (int i = 0; i < 3; ++i) {
        const int jj = j[i];
        const float dx = __fsub_rn(pos_x[jj*3+0], y0);
        const float dy = __fsub_rn(pos_x[jj*3+1], y1);
        const float dz = __fsub_rn(pos_x[jj*3+2], y2);
        const float sq = __fadd_rn(__fadd_rn(__fmul_rn(dx, dx), __fmul_rn(dy, dy)),
                                   __fmul_rn(dz, dz));
        w[i] = 1.0f / fmaxf(sq, 1e-16f);
    }
    const float inv_den = 1.0f / __fadd_rn(__fadd_rn(w[0], w[1]), w[2]);
    const float4* x4 = (const float4*)x;
    float4* o4 = (float4*)out;
    #pragma unroll
    for (int tt = 0; tt < 4; ++tt) {
        const float4 a = x4[j[0]*4 + tt];
        const float4 b = x4[j[1]*4 + tt];
        const float4 c = x4[j[2]*4 + tt];
        float4 r;
        r.x = (w[0]*a.x + w[1]*b.x + w[2]*c.x) * inv_den;
        r.y = (w[0]*a.y + w[1]*b.y + w[2]*c.y) * inv_den;
        r.z = (w[0]*a.z + w[1]*b.z + w[2]*c.z) * inv_den;
        r.w = (w[0]*a.w + w[1]*b.w + w[2]*c.w) * inv_den;
        o4[q*4 + tt] = r;
    }
}

// ========== K1: block 0 builds point grid; blocks 1..128 LDS-sort queries ==========
__global__ __launch_bounds__(512) void build_scatter(
    const float* __restrict__ pos_x, const float* __restrict__ pos_y, int ny,
    float4* __restrict__ wspt, int* __restrict__ wsidx, int* __restrict__ wcstart,
    unsigned short* __restrict__ scan2d, unsigned short* __restrict__ qsrt)
{
    __shared__ int sA[NCELL];
    __shared__ int sB[NCELL];
    const int t = threadIdx.x;

    if (blockIdx.x == 0) {
        // ---- point grid build (byte-identical to proven r6..r12 code) ----
        sA[t] = 0;
        __syncthreads();

        const float4* px4 = (const float4*)pos_x;
        const float4 v0 = px4[t*3+0], v1 = px4[t*3+1], v2 = px4[t*3+2];
        const float pxx[4] = {v0.x, v0.w, v1.z, v2.y};
        const float pyy[4] = {v0.y, v1.x, v1.w, v2.z};
        const float pzz[4] = {v0.z, v1.y, v2.x, v2.w};
        int cc[4];
        #pragma unroll
        for (int i = 0; i < 4; ++i) {
            cc[i] = (cell_of(pzz[i]) * GD + cell_of(pyy[i])) * GD + cell_of(pxx[i]);
            atomicAdd(&sA[cc[i]], 1);
        }
        __syncthreads();

        if (t < 64) {
            const int base = t * 8;
            int v[8];
            int run = 0;
            #pragma unroll
            for (int i = 0; i < 8; ++i) { run += sA[base + i]; v[i] = run; }
            int xs = run;
            #pragma unroll
            for (int off = 1; off < 64; off <<= 1) {
                const int y = __shfl_up(xs, off);
                if (t >= off) xs += y;
            }
            const int excl = xs - run;
            #pragma unroll
            for (int i = 0; i < 8; ++i) {
                const int inc = excl + v[i];
                wcstart[base + i + 1] = inc;
                sB[base + i] = inc - sA[base + i];
            }
            if (t == 0) wcstart[0] = 0;
        }
        __syncthreads();

        #pragma unroll
        for (int i = 0; i < 4; ++i) {
            const int p = t * 4 + i;
            const int pos = atomicAdd(&sB[cc[i]], 1);
            const float sx = __fadd_rn(__fadd_rn(__fmul_rn(pxx[i], pxx[i]),
                                                 __fmul_rn(pyy[i], pyy[i])),
                                       __fmul_rn(pzz[i], pzz[i]));
            wspt[pos] = make_float4(pxx[i], pyy[i], pzz[i], sx);
            wsidx[pos] = p;
        }
    } else {
        // ---- LDS counting sort of this block's 512 queries (no global atomics) ----
        const int b = blockIdx.x - 1;
        sA[t] = 0;
        __syncthreads();

        const int q = b * BQ + t;
        int c = -1;
        if (q < ny) {
            c = (cell_of(pos_y[q*3+2]) * GD + cell_of(pos_y[q*3+1])) * GD
              + cell_of(pos_y[q*3+0]);
            atomicAdd(&sA[c], 1);     // LDS atomic
        }
        __syncthreads();

        // exclusive scan of 512 counts (wave 0, proven pattern)
        if (t < 64) {
            const int base = t * 8;
            int v[8];
            int run = 0;
            #pragma unroll
            for (int i = 0; i < 8; ++i) { run += sA[base + i]; v[i] = run; }
            int xs = run;
            #pragma unroll
            for (int off = 1; off < 64; off <<= 1) {
                const int y = __shfl_up(xs, off);
                if (t >= off) xs += y;
            }
            const int excl = xs - run;
            #pragma unroll
            for (int i = 0; i < 8; ++i)
                sB[base + i] = excl + v[i] - sA[base + i];   // exclusive start
        }
        __syncthreads();

        // write the scan row (coalesced u16 stores); row fully rewritten per call
        scan2d[b * 513 + t] = (unsigned short)sB[t];
        if (t == 0) {
            int nb = ny - b * BQ;
            nb = nb < 0 ? 0 : (nb > BQ ? BQ : nb);
            scan2d[b * 513 + 512] = (unsigned short)nb;
        }
        __syncthreads();

        if (q < ny) {
            const int pos = atomicAdd(&sB[c], 1);   // LDS atomic rank
            qsrt[b * BQ + pos] = (unsigned short)q;
        }
    }
}

// ========== K2: one block per cell; software-pipelined phase A ==========
__global__ __launch_bounds__(128) void knn_cell(
    const float* __restrict__ x, const float* __restrict__ pos_x,
    const float* __restrict__ pos_y,
    const float4* __restrict__ wspt, const int* __restrict__ wsidx,
    const int* __restrict__ wcst,
    const unsigned short* __restrict__ scan2d, const unsigned short* __restrict__ qsrt,
    float* __restrict__ out)
{
    __shared__ float4 scand[CAP];
    __shared__ int    scidx[CAP];
    __shared__ int    rst[25], roff[26];
    __shared__ int    sL, sForce;
    __shared__ unsigned short qlist[QCAP];
    __shared__ int    wsum[2];

    const int t = threadIdx.x;
    const int c = blockIdx.x;
    const int cx = c & 7, cy = (c >> 3) & 7, cz = c >> 6;
    const int wave = t >> 6, lane = t & 63;

    // R=2 only for edge/corner cells (bcnt>=2) — r6/r7-proven rule; face cells
    // R=1 rely on the clearance bound + escalation (~1% of their queries)
    const int bcnt = (int)(cx == 0 || cx == GD-1) + (int)(cy == 0 || cy == GD-1)
                   + (int)(cz == 0 || cz == GD-1);
    const int R  = (bcnt >= 2) ? 2 : 1;
    const int W  = 2 * R + 1;
    const int NR = W * W;

    if (t < NR) {
        const int uz = cz + t / W - R, uy = cy + t % W - R;
        int st = 0, len = 0;
        if (((unsigned)uz < (unsigned)GD) & ((unsigned)uy < (unsigned)GD)) {
            const int xa = cx - R < 0 ? 0 : cx - R;
            const int xb = cx + R > GD - 1 ? GD - 1 : cx + R;
            const int cb = (uz * GD + uy) * GD;
            st  = wcst[cb + xa];
            len = wcst[cb + xb + 1] - st;
        }
        rst[t] = st;
        roff[t] = len;
    }
    __syncthreads();
    if (t == 0) {
        int o = 0;
        #pragma unroll 1
        for (int r = 0; r < NR; ++r) { const int l = roff[r]; roff[r] = o; o += l; }
        roff[NR] = o;
        sL = o > CAP ? CAP : o;
        sForce = (o > CAP) ? 1 : 0;
    }
    __syncthreads();

    // Lpad multiple of 16 for the 2-deep pipeline; (512+15)&~15 == 512 <= CAP
    const int L = sL, Lpad = (sL + 15) & ~15, force = sForce;
    for (int i = t; i < L; i += 128) {
        int r = 0;
        while (i >= roff[r + 1]) ++r;
        const int src = rst[r] + (i - roff[r]);
        scand[i] = wspt[src];
        scidx[i] = wsidx[src];
    }
    for (int i = L + t; i < Lpad; i += 128) {
        scand[i] = make_float4(0.f, 0.f, 0.f, 3e30f);  // sentinel: never inserted
        scidx[i] = 0x7fffffff;
    }

    // ---- query gather: lane t = source block t; segment [s0, s0+cnt) ----
    const int s0  = (int)scan2d[t * 513 + c];
    const int cnt = (int)scan2d[t * 513 + c + 1] - s0;
    int inc = cnt;
    #pragma unroll
    for (int off = 1; off < 64; off <<= 1) {
        const int y = __shfl_up(inc, off);
        if (lane >= off) inc += y;
    }
    if (lane == 63) wsum[wave] = inc;
    __syncthreads();
    const int base  = inc - cnt + (wave ? wsum[0] : 0);
    const int total = wsum[0] + wsum[1];

    for (int S = 0; S < total; S += QCAP) {
        __syncthreads();
        for (int k = 0; k < cnt; ++k) {
            const int g = base + k;
            if (g >= S && g < S + QCAP) qlist[g - S] = qsrt[t * BQ + s0 + k];
        }
        __syncthreads();
        const int n = (total - S) < QCAP ? (total - S) : QCAP;

        for (int i0 = wave * 64; i0 < n; i0 += 128) {
            const int slot = i0 + lane;
            const bool active = slot < n;
            const int q = active ? (int)qlist[slot] : 0;
            float y0 = 0.f, y1 = 0.f, y2 = 0.f;
            if (active) { y0 = pos_y[q*3+0]; y1 = pos_y[q*3+1]; y2 = pos_y[q*3+2]; }
            const float sy = __fadd_rn(__fadd_rn(__fmul_rn(y0, y0), __fmul_rn(y1, y1)),
                                       __fmul_rn(y2, y2));

            // exact clearance to staged cube (proven r9..r12)
            float clr = 1e30f;
            if (cx - R > 0)      clr = fminf(clr, y0 - (float)(cx - R) * HCELL);
            if (cx + R < GD - 1) clr = fminf(clr, (float)(cx + R + 1) * HCELL - y0);
            if (cy - R > 0)      clr = fminf(clr, y1 - (float)(cy - R) * HCELL);
            if (cy + R < GD - 1) clr = fminf(clr, (float)(cy + R + 1) * HCELL - y1);
            if (cz - R > 0)      clr = fminf(clr, y2 - (float)(cz - R) * HCELL);
            if (cz + R < GD - 1) clr = fminf(clr, (float)(cz + R + 1) * HCELL - y2);
            const float thr = clr * clr;

            uint64_t b0 = ~0ull, b1 = ~0ull, b2 = ~0ull;

            // ---- phase A: 2-deep software pipeline over 8-candidate batches.
            // Batch loads independent (one lgkmcnt drain per batch); keys
            // computed independently; only the short insert chains are serial.
            // Candidate d2 rounding identical to every passing round.
            float4 pA[8]; int iA[8];
            float4 pB[8]; int iB[8];
            #pragma unroll
            for (int u = 0; u < 8; ++u) { pA[u] = scand[u]; iA[u] = scidx[u]; }

            for (int j = 0; j < Lpad; j += 16) {
                #pragma unroll
                for (int u = 0; u < 8; ++u) { pB[u] = scand[j+8+u]; iB[u] = scidx[j+8+u]; }
                {
                    uint64_t kk[8];
                    #pragma unroll
                    for (int u = 0; u < 8; ++u) {
                        const float dot = __fmaf_rn(y2, pA[u].z,
                                          __fmaf_rn(y1, pA[u].y, __fmul_rn(y0, pA[u].x)));
                        const float d = __fmaf_rn(-2.0f, dot, __fadd_rn(sy, pA[u].w));
                        kk[u] = ((uint64_t)mono(d) << 32) | (uint32_t)iA[u];
                    }
                    #pragma unroll
                    for (int u = 0; u < 8; ++u) {
                        const uint64_t k2 = kk[u];
                        const bool lt0 = k2 < b0, lt1 = k2 < b1, lt2 = k2 < b2;
                        b2 = lt1 ? b1 : (lt2 ? k2 : b2);
                        b1 = lt0 ? b0 : (lt1 ? k2 : b1);
                        b0 = lt0 ? k2 : b0;
                    }
                }
                if (j + 16 < Lpad) {
                    #pragma unroll
                    for (int u = 0; u < 8; ++u) { pA[u] = scand[j+16+u]; iA[u] = scidx[j+16+u]; }
                }
                {
                    uint64_t kk[8];
                    #pragma unroll
                    for (int u = 0; u < 8; ++u) {
                        const float dot = __fmaf_rn(y2, pB[u].z,
                                          __fmaf_rn(y1, pB[u].y, __fmul_rn(y0, pB[u].x)));
                        const float d = __fmaf_rn(-2.0f, dot, __fadd_rn(sy, pB[u].w));
                        kk[u] = ((uint64_t)mono(d) << 32) | (uint32_t)iB[u];
                    }
                    #pragma unroll
                    for (int u = 0; u < 8; ++u) {
                        const uint64_t k2 = kk[u];
                        const bool lt0 = k2 < b0, lt1 = k2 < b1, lt2 = k2 < b2;
                        b2 = lt1 ? b1 : (lt2 ? k2 : b2);
                        b1 = lt0 ? b0 : (lt1 ? k2 : b1);
                        b0 = lt0 ? k2 : b0;
                    }
                }
            }

            // escalation (proven): wave-coop terminal brute with dedup
            bool esc = false;
            if (active) {
                const bool have3 = (b2 != ~0ull);
                const float b2d = unmono((uint32_t)(b2 >> 32));
                esc = !(have3 && (b2d + 1e-4f < thr)) | (force != 0);
            }
            unsigned long long bal = __ballot(esc);
            while (bal) {
                const int e = __ffsll(bal) - 1;
                bal &= bal - 1;
                const float ey0 = __shfl(y0, e), ey1 = __shfl(y1, e), ey2 = __shfl(y2, e);
                const float esy = __shfl(sy, e);
                uint64_t m0 = shfl_u64(b0, e), m1 = shfl_u64(b1, e), m2 = shfl_u64(b2, e);
                for (int p = lane; p < NXP; p += 64) {
                    const float4 pt = wspt[p];
                    const float dot = __fmaf_rn(ey2, pt.z,
                                      __fmaf_rn(ey1, pt.y, __fmul_rn(ey0, pt.x)));
                    const float d = __fmaf_rn(-2.0f, dot, __fadd_rn(esy, pt.w));
                    const uint64_t kk = ((uint64_t)mono(d) << 32) | (uint32_t)wsidx[p];
                    if (kk < m2) ins_dedup(kk, m0, m1, m2);
                }
                #pragma unroll
                for (int mask = 1; mask < 64; mask <<= 1) {
                    const uint64_t r0 = shfl_xor_u64(m0, mask);
                    const uint64_t r1 = shfl_xor_u64(m1, mask);
                    const uint64_t r2 = shfl_xor_u64(m2, mask);
                    ins_dedup(r0, m0, m1, m2);
                    ins_dedup(r1, m0, m1, m2);
                    ins_dedup(r2, m0, m1, m2);
                }
                if (lane == e) { b0 = m0; b1 = m1; b2 = m2; }
            }

            if (active) write_out_full(x, pos_x, out, q, y0, y1, y2, b0, b1, b2);
        }
    }
}

// =============== fallback (round-7 kernel, 43 KB ws; proven 34 us) ===============
#define QBLK  512
#define SEG   8
#define QPB   (QBLK / SEG)
#define QGRID 512

__device__ __forceinline__ void merge_group8(uint64_t& b0, uint64_t& b1, uint64_t& b2) {
    #pragma unroll
    for (int mask = 1; mask < SEG; mask <<= 1) {
        const uint64_t r0 = shfl_xor_u64(b0, mask);
        const uint64_t r1 = shfl_xor_u64(b1, mask);
        const uint64_t r2 = shfl_xor_u64(b2, mask);
        ins_dedup(r0, b0, b1, b2);
        ins_dedup(r1, b0, b1, b2);
        ins_dedup(r2, b0, b1, b2);
    }
}

__global__ __launch_bounds__(QBLK) void knn_query_fb(
    const float* __restrict__ x, const float* __restrict__ pos_x,
    const float* __restrict__ pos_y,
    const float4* __restrict__ wspt, const int* __restrict__ wsidx,
    const int* __restrict__ wcstart,
    float* __restrict__ out, int ny)
{
    __shared__ float4 spt[NXP];
    __shared__ int    sidx[NXP];
    __shared__ int    cstart[NCELL + 1];

    const int t = threadIdx.x;
    for (int i = t; i < NXP; i += QBLK) spt[i] = wspt[i];
    for (int i = t; i < NXP; i += QBLK) sidx[i] = wsidx[i];
    for (int i = t; i < NCELL + 1; i += QBLK) cstart[i] = wcstart[i];
    __syncthreads();

    const int s = t & (SEG - 1);
    const int nbatch = (ny + QPB - 1) / QPB;

    for (int batch = blockIdx.x; batch < nbatch; batch += gridDim.x) {
        const int q = batch * QPB + (t >> 3);
        if (q >= ny) continue;

        const float y0 = pos_y[q*3+0], y1 = pos_y[q*3+1], y2 = pos_y[q*3+2];
        const float sy = __fadd_rn(__fadd_rn(__fmul_rn(y0, y0), __fmul_rn(y1, y1)),
                                   __fmul_rn(y2, y2));
        const int cx = cell_of(y0), cy = cell_of(y1), cz = cell_of(y2);

        uint64_t b0 = ~0ull, b1 = ~0ull, b2 = ~0ull;

#define EVAL_BODY(P, INS)                                                       \
        {                                                                       \
            const float4 pt = spt[P];                                           \
            const float dot = __fmaf_rn(y2, pt.z,                               \
                              __fmaf_rn(y1, pt.y, __fmul_rn(y0, pt.x)));        \
            const float d = __fmaf_rn(-2.0f, dot, __fadd_rn(sy, pt.w));         \
            const uint64_t kk = ((uint64_t)mono(d) << 32) | (uint32_t)sidx[P];  \
            if (kk < b2) INS(kk, b0, b1, b2);                                   \
        }

        const int x0 = cx - 1 < 0 ? 0 : cx - 1;
        const int x1 = cx + 1 > GD - 1 ? GD - 1 : cx + 1;
        #pragma unroll
        for (int r = 0; r < 9; ++r) {
            const int uz = cz + r / 3 - 1, uy = cy + r % 3 - 1;
            int st = 0, en = 0;
            if (((unsigned)uz < (unsigned)GD) & ((unsigned)uy < (unsigned)GD)) {
                const int cb = (uz * GD + uy) * GD;
                st = cstart[cb + x0];
                en = cstart[cb + x1 + 1];
            }
            for (int p = st + s; p < en; p += SEG) EVAL_BODY(p, ins_fast)
        }
        merge_group8(b0, b1, b2);

        {
            bool have3 = (b2 != ~0ull);
            float b2d = unmono((uint32_t)(b2 >> 32));
            if (!(have3 && (b2d + 1e-4f < 0.015625f))) {
                for (int r = 0; r < 25; ++r) {
                    const int dzi = r / 5 - 2, dyi = r % 5 - 2;
                    const int uz = cz + dzi, uy = cy + dyi;
                    if (((unsigned)uz >= (unsigned)GD) | ((unsigned)uy >= (unsigned)GD))
                        continue;
                    const int cb = (uz * GD + uy) * GD;
                    if (dzi == -2 || dzi == 2 || dyi == -2 || dyi == 2) {
                        const int xa = cx - 2 < 0 ? 0 : cx - 2;
                        const int xb = cx + 2 > GD - 1 ? GD - 1 : cx + 2;
                        const int st = cstart[cb + xa], en = cstart[cb + xb + 1];
                        for (int p = st + s; p < en; p += SEG) EVAL_BODY(p, ins_fast)
                    } else {
                        if (cx - 2 >= 0) {
                            const int st = cstart[cb + cx - 2], en = cstart[cb + cx - 1];
                            for (int p = st + s; p < en; p += SEG) EVAL_BODY(p, ins_fast)
                        }
                        if (cx + 2 <= GD - 1) {
                            const int st = cstart[cb + cx + 2], en = cstart[cb + cx + 3];
                            for (int p = st + s; p < en; p += SEG) EVAL_BODY(p, ins_fast)
                        }
                    }
                }
                merge_group8(b0, b1, b2);

                have3 = (b2 != ~0ull);
                b2d = unmono((uint32_t)(b2 >> 32));
                if (!(have3 && (b2d + 1e-4f < 0.0625f))) {
                    for (int p = s; p < NXP; p += SEG) EVAL_BODY(p, ins_dedup)
                    merge_group8(b0, b1, b2);
                }
            }
        }
#undef EVAL_BODY

        const int j[3] = { (int)(uint32_t)b0, (int)(uint32_t)b1, (int)(uint32_t)b2 };
        float w[3];
        #pragma unroll
        for (int i = 0; i < 3; ++i) {
            const int jj = j[i];
            const float dx = __fsub_rn(pos_x[jj*3+0], y0);
            const float dy = __fsub_rn(pos_x[jj*3+1], y1);
            const float dz = __fsub_rn(pos_x[jj*3+2], y2);
            const float sq = __fadd_rn(__fadd_rn(__fmul_rn(dx, dx), __fmul_rn(dy, dy)),
                                       __fmul_rn(dz, dz));
            w[i] = 1.0f / fmaxf(sq, 1e-16f);
        }
        const float inv_den = 1.0f / __fadd_rn(__fadd_rn(w[0], w[1]), w[2]);

        const float2* x2 = (const float2*)x;
        float2* o2 = (float2*)out;
        const float2 a = x2[j[0]*8 + s];
        const float2 b = x2[j[1]*8 + s];
        const float2 c = x2[j[2]*8 + s];
        float2 rr;
        rr.x = (w[0]*a.x + w[1]*b.x + w[2]*c.x) * inv_den;
        rr.y = (w[0]*a.y + w[1]*b.y + w[2]*c.y) * inv_den;
        o2[q*8 + s] = rr;
    }
}

extern "C" void kernel_launch(void* const* d_in, const int* in_sizes, int n_in,
                              void* d_out, int out_size, void* d_ws, size_t ws_size,
                              hipStream_t stream) {
    const float* x     = (const float*)d_in[0];  // [2048, 16]
    const float* pos_x = (const float*)d_in[1];  // [2048, 3]
    const float* pos_y = (const float*)d_in[2];  // [65536, 3]
    float* out = (float*)d_out;
    const int ny = in_sizes[2] / 3;  // 65536

    float4*         wspt   = (float4*)        ((char*)d_ws + WS_SPT);
    int*            wsidx  = (int*)           ((char*)d_ws + WS_SIDX);
    int*            wcst   = (int*)           ((char*)d_ws + WS_CST);
    unsigned short* scan2d = (unsigned short*)((char*)d_ws + WS_SCN);
    unsigned short* qsrt   = (unsigned short*)((char*)d_ws + WS_QSRT);

    if (ws_size >= (size_t)WS_NEED && ny <= NQB * BQ) {
        build_scatter<<<1 + NQB, 512, 0, stream>>>(pos_x, pos_y, ny,
                                                   wspt, wsidx, wcst, scan2d, qsrt);
        knn_cell<<<NCELL, 128, 0, stream>>>(x, pos_x, pos_y, wspt, wsidx, wcst,
                                            scan2d, qsrt, out);
    } else {
        build_scatter<<<1, 512, 0, stream>>>(pos_x, pos_y, 0,
                                             wspt, wsidx, wcst, scan2d, qsrt);
        knn_query_fb<<<QGRID, QBLK, 0, stream>>>(x, pos_x, pos_y, wspt, wsidx, wcst,
                                                 out, ny);
    }
}

// Round 15
// 33.596 us; speedup vs baseline: 2.8311x; 1.1960x over previous
//
#include <hip/hip_runtime.h>
#include <stdint.h>

#define NXP   2048   // pivotal (source) nodes
#define NC    16     // feature channels
#define GD    8      // grid cells per axis
#define NCELL (GD*GD*GD)   // 512
#define CAP   512    // max staged candidates per cell block
#define QCAP  512    // query LDS list capacity per pass
#define HCELL 0.125f
#define NQB   128    // query scatter blocks
#define BQ    512    // queries per scatter block

// ---- d_ws layout (bytes); total 305472 <= 312832 (proven available, r9) ----
#define WS_SPT   0        // float4[2048]
#define WS_SIDX  32768    // int[2048]
#define WS_CST   40960    // int[513]                     (ends 43012)
#define WS_SCN   43072    // u16[128][513] per-block cell scan (ends 174400)
#define WS_QSRT  174400   // u16[65536] block-sorted query ids (ends 305472)
#define WS_NEED  305472

__device__ __forceinline__ int cell_of(float v) {
    int c = (int)(v * (float)GD);
    c = c > GD - 1 ? GD - 1 : c;
    return c < 0 ? 0 : c;
}
__device__ __forceinline__ uint32_t mono(float d) {
    uint32_t b = __float_as_uint(d);
    return b ^ (uint32_t)(((int32_t)b >> 31) | 0x80000000);
}
__device__ __forceinline__ float unmono(uint32_t m) {
    uint32_t b = (m & 0x80000000u) ? (m ^ 0x80000000u) : ~m;
    return __uint_as_float(b);
}
__device__ __forceinline__ void ins_fast(uint64_t k, uint64_t& b0, uint64_t& b1, uint64_t& b2) {
    const bool lt0 = k < b0, lt1 = k < b1;
    b2 = lt1 ? b1 : k;
    b1 = lt0 ? b0 : (lt1 ? k : b1);
    b0 = lt0 ? k  : b0;
}
__device__ __forceinline__ void ins_dedup(uint64_t k, uint64_t& b0, uint64_t& b1, uint64_t& b2) {
    if (k == b0 || k == b1 || k == b2) return;
    const bool lt0 = k < b0, lt1 = k < b1, lt2 = k < b2;
    b2 = lt1 ? b1 : (lt2 ? k : b2);
    b1 = lt0 ? b0 : (lt1 ? k : b1);
    b0 = lt0 ? k  : b0;
}
__device__ __forceinline__ uint64_t shfl_u64(uint64_t v, int src) {
    const int lo = __shfl((int)(uint32_t)v, src);
    const int hi = __shfl((int)(uint32_t)(v >> 32), src);
    return ((uint64_t)(uint32_t)hi << 32) | (uint32_t)lo;
}
__device__ __forceinline__ uint64_t shfl_xor_u64(uint64_t v, int mask) {
    const int lo = __shfl_xor((int)(uint32_t)v, mask);
    const int hi = __shfl_xor((int)(uint32_t)(v >> 32), mask);
    return ((uint64_t)(uint32_t)hi << 32) | (uint32_t)lo;
}

// full 16-channel epilogue (used by escalation/overflow paths)
__device__ __forceinline__ void write_out_full(
    const float* __restrict__ x, const float* __restrict__ pos_x,
    float* __restrict__ out, int q, float y0, float y1, float y2,
    uint64_t b0, uint64_t b1, uint64_t b2)
{
    const int j[3] = { (int)(uint32_t)b0, (int)(uint32_t)b1, (int)(uint32_t)b2 };
    float w[3];
    #pragma unroll
    for (int i = 0; i < 3; ++i) {
        const int jj = j[i];
        const float dx = __fsub_rn(pos_x[jj*3+0], y0);
        const float dy = __fsub_rn(pos_x[jj*3+1], y1);
        const float dz = __fsub_rn(pos_x[jj*3+2], y2);
        const float sq = __fadd_rn(__fadd_rn(__fmul_rn(dx, dx), __fmul_rn(dy, dy)),
                                   __fmul_rn(dz, dz));
        w[i] = 1.0f / fmaxf(sq, 1e-16f);
    }
    const float inv_den = 1.0f / __fadd_rn(__fadd_rn(w[0], w[1]), w[2]);
    const float4* x4 = (const float4*)x;
    float4* o4 = (float4*)out;
    #pragma unroll
    for (int tt = 0; tt < 4; ++tt) {
        const float4 a = x4[j[0]*4 + tt];
        const float4 b = x4[j[1]*4 + tt];
        const float4 c = x4[j[2]*4 + tt];
        float4 r;
        r.x = (w[0]*a.x + w[1]*b.x + w[2]*c.x) * inv_den;
        r.y = (w[0]*a.y + w[1]*b.y + w[2]*c.y) * inv_den;
        r.z = (w[0]*a.z + w[1]*b.z + w[2]*c.z) * inv_den;
        r.w = (w[0]*a.w + w[1]*b.w + w[2]*c.w) * inv_den;
        o4[q*4 + tt] = r;
    }
}

// ========== K1: block 0 builds point grid; blocks 1..128 LDS-sort queries ==========
__global__ __launch_bounds__(512) void build_scatter(
    const float* __restrict__ pos_x, const float* __restrict__ pos_y, int ny,
    float4* __restrict__ wspt, int* __restrict__ wsidx, int* __restrict__ wcstart,
    unsigned short* __restrict__ scan2d, unsigned short* __restrict__ qsrt)
{
    __shared__ int sA[NCELL];
    __shared__ int sB[NCELL];
    const int t = threadIdx.x;

    if (blockIdx.x == 0) {
        // ---- point grid build (byte-identical to proven r6..r14 code) ----
        sA[t] = 0;
        __syncthreads();

        const float4* px4 = (const float4*)pos_x;
        const float4 v0 = px4[t*3+0], v1 = px4[t*3+1], v2 = px4[t*3+2];
        const float pxx[4] = {v0.x, v0.w, v1.z, v2.y};
        const float pyy[4] = {v0.y, v1.x, v1.w, v2.z};
        const float pzz[4] = {v0.z, v1.y, v2.x, v2.w};
        int cc[4];
        #pragma unroll
        for (int i = 0; i < 4; ++i) {
            cc[i] = (cell_of(pzz[i]) * GD + cell_of(pyy[i])) * GD + cell_of(pxx[i]);
            atomicAdd(&sA[cc[i]], 1);
        }
        __syncthreads();

        if (t < 64) {
            const int base = t * 8;
            int v[8];
            int run = 0;
            #pragma unroll
            for (int i = 0; i < 8; ++i) { run += sA[base + i]; v[i] = run; }
            int xs = run;
            #pragma unroll
            for (int off = 1; off < 64; off <<= 1) {
                const int y = __shfl_up(xs, off);
                if (t >= off) xs += y;
            }
            const int excl = xs - run;
            #pragma unroll
            for (int i = 0; i < 8; ++i) {
                const int inc = excl + v[i];
                wcstart[base + i + 1] = inc;
                sB[base + i] = inc - sA[base + i];
            }
            if (t == 0) wcstart[0] = 0;
        }
        __syncthreads();

        #pragma unroll
        for (int i = 0; i < 4; ++i) {
            const int p = t * 4 + i;
            const int pos = atomicAdd(&sB[cc[i]], 1);
            const float sx = __fadd_rn(__fadd_rn(__fmul_rn(pxx[i], pxx[i]),
                                                 __fmul_rn(pyy[i], pyy[i])),
                                       __fmul_rn(pzz[i], pzz[i]));
            wspt[pos] = make_float4(pxx[i], pyy[i], pzz[i], sx);
            wsidx[pos] = p;
        }
    } else {
        // ---- LDS counting sort of this block's 512 queries (no global atomics) ----
        const int b = blockIdx.x - 1;
        sA[t] = 0;
        __syncthreads();

        const int q = b * BQ + t;
        int c = -1;
        if (q < ny) {
            c = (cell_of(pos_y[q*3+2]) * GD + cell_of(pos_y[q*3+1])) * GD
              + cell_of(pos_y[q*3+0]);
            atomicAdd(&sA[c], 1);     // LDS atomic
        }
        __syncthreads();

        if (t < 64) {
            const int base = t * 8;
            int v[8];
            int run = 0;
            #pragma unroll
            for (int i = 0; i < 8; ++i) { run += sA[base + i]; v[i] = run; }
            int xs = run;
            #pragma unroll
            for (int off = 1; off < 64; off <<= 1) {
                const int y = __shfl_up(xs, off);
                if (t >= off) xs += y;
            }
            const int excl = xs - run;
            #pragma unroll
            for (int i = 0; i < 8; ++i)
                sB[base + i] = excl + v[i] - sA[base + i];   // exclusive start
        }
        __syncthreads();

        scan2d[b * 513 + t] = (unsigned short)sB[t];
        if (t == 0) {
            int nb = ny - b * BQ;
            nb = nb < 0 ? 0 : (nb > BQ ? BQ : nb);
            scan2d[b * 513 + 512] = (unsigned short)nb;
        }
        __syncthreads();

        if (q < ny) {
            const int pos = atomicAdd(&sB[c], 1);   // LDS atomic rank
            qsrt[b * BQ + pos] = (unsigned short)q;
        }
    }
}

// ========== K2: one block per cell; 4-lane group per query, 8 waves ==========
__global__ __launch_bounds__(512) void knn_cell(
    const float* __restrict__ x, const float* __restrict__ pos_x,
    const float* __restrict__ pos_y,
    const float4* __restrict__ wspt, const int* __restrict__ wsidx,
    const int* __restrict__ wcst,
    const unsigned short* __restrict__ scan2d, const unsigned short* __restrict__ qsrt,
    float* __restrict__ out)
{
    __shared__ float4 scand[CAP];
    __shared__ int    scidx[CAP];
    __shared__ int    rst[25], roff[26];
    __shared__ int    sL, sForce;
    __shared__ unsigned short qlist[QCAP];
    __shared__ int    wsum[2];

    const int t = threadIdx.x;
    const int c = blockIdx.x;
    const int cx = c & 7, cy = (c >> 3) & 7, cz = c >> 6;
    const int lane = t & 63;   // lane in wave
    const int grp  = t >> 2;   // query group 0..127
    const int s    = t & 3;    // segment within group

    // R=2 only for edge/corner cells (bcnt>=2) — r6/r7-proven rule
    const int bcnt = (int)(cx == 0 || cx == GD-1) + (int)(cy == 0 || cy == GD-1)
                   + (int)(cz == 0 || cz == GD-1);
    const int R  = (bcnt >= 2) ? 2 : 1;
    const int W  = 2 * R + 1;
    const int NR = W * W;

    if (t < NR) {
        const int uz = cz + t / W - R, uy = cy + t % W - R;
        int st = 0, len = 0;
        if (((unsigned)uz < (unsigned)GD) & ((unsigned)uy < (unsigned)GD)) {
            const int xa = cx - R < 0 ? 0 : cx - R;
            const int xb = cx + R > GD - 1 ? GD - 1 : cx + R;
            const int cb = (uz * GD + uy) * GD;
            st  = wcst[cb + xa];
            len = wcst[cb + xb + 1] - st;
        }
        rst[t] = st;
        roff[t] = len;
    }
    __syncthreads();
    if (t == 0) {
        int o = 0;
        #pragma unroll 1
        for (int r = 0; r < NR; ++r) { const int l = roff[r]; roff[r] = o; o += l; }
        roff[NR] = o;
        sL = o > CAP ? CAP : o;
        sForce = (o > CAP) ? 1 : 0;
    }
    __syncthreads();

    // Lpad multiple of 32 (per-lane count multiple of 8); (512+31)&~31 == 512 <= CAP
    const int L = sL, Lpad = (sL + 31) & ~31, force = sForce;
    for (int i = t; i < L; i += 512) {
        int r = 0;
        while (i >= roff[r + 1]) ++r;
        const int src = rst[r] + (i - roff[r]);
        scand[i] = wspt[src];
        scidx[i] = wsidx[src];
    }
    for (int i = L + t; i < Lpad; i += 512) {
        scand[i] = make_float4(0.f, 0.f, 0.f, 3e30f);  // sentinel: never inserted
        scidx[i] = 0x7fffffff;
    }

    // ---- query gather (threads 0..127): lane t = source block; seg [s0, s0+cnt) ----
    int base = 0, cnt = 0, s0 = 0;
    if (t < 128) {
        s0  = (int)scan2d[t * 513 + c];
        cnt = (int)scan2d[t * 513 + c + 1] - s0;
        int inc = cnt;
        #pragma unroll
        for (int off = 1; off < 64; off <<= 1) {
            const int y = __shfl_up(inc, off);
            if (lane >= off) inc += y;
        }
        if (lane == 63) wsum[t >> 6] = inc;
        base = inc - cnt;
    }
    __syncthreads();
    if (t >= 64 && t < 128) base += wsum[0];
    const int total = wsum[0] + wsum[1];

    for (int S = 0; S < total; S += QCAP) {
        __syncthreads();
        if (t < 128) {
            for (int k = 0; k < cnt; ++k) {
                const int g = base + k;
                if (g >= S && g < S + QCAP) qlist[g - S] = qsrt[t * BQ + s0 + k];
            }
        }
        __syncthreads();
        const int n = (total - S) < QCAP ? (total - S) : QCAP;

        for (int i0 = 0; i0 < n; i0 += 128) {
            const int slot = i0 + grp;
            const bool active = slot < n;
            const int q = active ? (int)qlist[slot] : 0;
            float y0 = 0.f, y1 = 0.f, y2 = 0.f;
            if (active) { y0 = pos_y[q*3+0]; y1 = pos_y[q*3+1]; y2 = pos_y[q*3+2]; }
            const float sy = __fadd_rn(__fadd_rn(__fmul_rn(y0, y0), __fmul_rn(y1, y1)),
                                       __fmul_rn(y2, y2));

            // exact clearance to staged cube (proven r9..r14)
            float clr = 1e30f;
            if (cx - R > 0)      clr = fminf(clr, y0 - (float)(cx - R) * HCELL);
            if (cx + R < GD - 1) clr = fminf(clr, (float)(cx + R + 1) * HCELL - y0);
            if (cy - R > 0)      clr = fminf(clr, y1 - (float)(cy - R) * HCELL);
            if (cy + R < GD - 1) clr = fminf(clr, (float)(cy + R + 1) * HCELL - y1);
            if (cz - R > 0)      clr = fminf(clr, y2 - (float)(cz - R) * HCELL);
            if (cz + R < GD - 1) clr = fminf(clr, (float)(cz + R + 1) * HCELL - y2);
            const float thr = clr * clr;

            uint64_t b0 = ~0ull, b1 = ~0ull, b2 = ~0ull;

            // ---- phase A: lane scans its quarter (stride-4 interleave),
            // 2-deep pipeline over 4-candidate batches. d2 rounding identical
            // to every passing round.
            const int PL = Lpad >> 2;    // per-lane candidates, multiple of 8
            float4 pA[4]; int iA[4];
            float4 pB[4]; int iB[4];
            #pragma unroll
            for (int u = 0; u < 4; ++u) {
                const int id = s + 4*u;
                pA[u] = scand[id]; iA[u] = scidx[id];
            }

            for (int j = 0; j < PL; j += 8) {
                #pragma unroll
                for (int u = 0; u < 4; ++u) {
                    const int id = s + 4*(j + 4 + u);
                    pB[u] = scand[id]; iB[u] = scidx[id];
                }
                {
                    uint64_t kk[4];
                    #pragma unroll
                    for (int u = 0; u < 4; ++u) {
                        const float dot = __fmaf_rn(y2, pA[u].z,
                                          __fmaf_rn(y1, pA[u].y, __fmul_rn(y0, pA[u].x)));
                        const float d = __fmaf_rn(-2.0f, dot, __fadd_rn(sy, pA[u].w));
                        kk[u] = ((uint64_t)mono(d) << 32) | (uint32_t)iA[u];
                    }
                    #pragma unroll
                    for (int u = 0; u < 4; ++u) {
                        const uint64_t k2 = kk[u];
                        const bool lt0 = k2 < b0, lt1 = k2 < b1, lt2 = k2 < b2;
                        b2 = lt1 ? b1 : (lt2 ? k2 : b2);
                        b1 = lt0 ? b0 : (lt1 ? k2 : b1);
                        b0 = lt0 ? k2 : b0;
                    }
                }
                if (j + 8 < PL) {
                    #pragma unroll
                    for (int u = 0; u < 4; ++u) {
                        const int id = s + 4*(j + 8 + u);
                        pA[u] = scand[id]; iA[u] = scidx[id];
                    }
                }
                {
                    uint64_t kk[4];
                    #pragma unroll
                    for (int u = 0; u < 4; ++u) {
                        const float dot = __fmaf_rn(y2, pB[u].z,
                                          __fmaf_rn(y1, pB[u].y, __fmul_rn(y0, pB[u].x)));
                        const float d = __fmaf_rn(-2.0f, dot, __fadd_rn(sy, pB[u].w));
                        kk[u] = ((uint64_t)mono(d) << 32) | (uint32_t)iB[u];
                    }
                    #pragma unroll
                    for (int u = 0; u < 4; ++u) {
                        const uint64_t k2 = kk[u];
                        const bool lt0 = k2 < b0, lt1 = k2 < b1, lt2 = k2 < b2;
                        b2 = lt1 ? b1 : (lt2 ? k2 : b2);
                        b1 = lt0 ? b0 : (lt1 ? k2 : b1);
                        b0 = lt0 ? k2 : b0;
                    }
                }
            }

            // merge across the 4-lane group (masks 1,2 stay in-group); dedup
            // makes overlap-free merging safe (r5-proven)
            #pragma unroll
            for (int mask = 1; mask < 4; mask <<= 1) {
                const uint64_t r0 = shfl_xor_u64(b0, mask);
                const uint64_t r1 = shfl_xor_u64(b1, mask);
                const uint64_t r2 = shfl_xor_u64(b2, mask);
                ins_dedup(r0, b0, b1, b2);
                ins_dedup(r1, b0, b1, b2);
                ins_dedup(r2, b0, b1, b2);
            }

            // escalation (proven): only group leader flags; wave-coop brute
            bool esc = false;
            if (active && s == 0) {
                const bool have3 = (b2 != ~0ull);
                const float b2d = unmono((uint32_t)(b2 >> 32));
                esc = !(have3 && (b2d + 1e-4f < thr)) | (force != 0);
            }
            unsigned long long bal = __ballot(esc);
            while (bal) {
                const int e = __ffsll(bal) - 1;
                bal &= bal - 1;
                const float ey0 = __shfl(y0, e), ey1 = __shfl(y1, e), ey2 = __shfl(y2, e);
                const float esy = __shfl(sy, e);
                uint64_t m0 = shfl_u64(b0, e), m1 = shfl_u64(b1, e), m2 = shfl_u64(b2, e);
                for (int p = lane; p < NXP; p += 64) {
                    const float4 pt = wspt[p];
                    const float dot = __fmaf_rn(ey2, pt.z,
                                      __fmaf_rn(ey1, pt.y, __fmul_rn(ey0, pt.x)));
                    const float d = __fmaf_rn(-2.0f, dot, __fadd_rn(esy, pt.w));
                    const uint64_t kk = ((uint64_t)mono(d) << 32) | (uint32_t)wsidx[p];
                    if (kk < m2) ins_dedup(kk, m0, m1, m2);
                }
                #pragma unroll
                for (int mask = 1; mask < 64; mask <<= 1) {
                    const uint64_t r0 = shfl_xor_u64(m0, mask);
                    const uint64_t r1 = shfl_xor_u64(m1, mask);
                    const uint64_t r2 = shfl_xor_u64(m2, mask);
                    ins_dedup(r0, m0, m1, m2);
                    ins_dedup(r1, m0, m1, m2);
                    ins_dedup(r2, m0, m1, m2);
                }
                if (lane == e) { b0 = m0; b1 = m1; b2 = m2; }
            }
            // re-broadcast group leader's triple (identity for non-escalated)
            {
                const int ldr = lane & ~3;
                b0 = shfl_u64(b0, ldr);
                b1 = shfl_u64(b1, ldr);
                b2 = shfl_u64(b2, ldr);
            }

            // epilogue: each lane writes channel quarter s (coalesced 64B/query)
            if (active) {
                const int j0 = (int)(uint32_t)b0, j1 = (int)(uint32_t)b1,
                          j2 = (int)(uint32_t)b2;
                float w[3];
                const int jj[3] = { j0, j1, j2 };
                #pragma unroll
                for (int i = 0; i < 3; ++i) {
                    const float dx = __fsub_rn(pos_x[jj[i]*3+0], y0);
                    const float dy = __fsub_rn(pos_x[jj[i]*3+1], y1);
                    const float dz = __fsub_rn(pos_x[jj[i]*3+2], y2);
                    const float sq = __fadd_rn(__fadd_rn(__fmul_rn(dx, dx),
                                                         __fmul_rn(dy, dy)),
                                               __fmul_rn(dz, dz));
                    w[i] = 1.0f / fmaxf(sq, 1e-16f);
                }
                const float inv_den = 1.0f / __fadd_rn(__fadd_rn(w[0], w[1]), w[2]);
                const float4* x4 = (const float4*)x;
                float4* o4 = (float4*)out;
                const float4 a = x4[j0*4 + s];
                const float4 b = x4[j1*4 + s];
                const float4 cc2 = x4[j2*4 + s];
                float4 r;
                r.x = (w[0]*a.x + w[1]*b.x + w[2]*cc2.x) * inv_den;
                r.y = (w[0]*a.y + w[1]*b.y + w[2]*cc2.y) * inv_den;
                r.z = (w[0]*a.z + w[1]*b.z + w[2]*cc2.z) * inv_den;
                r.w = (w[0]*a.w + w[1]*b.w + w[2]*cc2.w) * inv_den;
                o4[q*4 + s] = r;
            }
        }
    }
}

// =============== fallback (round-7 kernel, 43 KB ws; proven 34 us) ===============
#define QBLK  512
#define SEG   8
#define QPB   (QBLK / SEG)
#define QGRID 512

__device__ __forceinline__ void merge_group8(uint64_t& b0, uint64_t& b1, uint64_t& b2) {
    #pragma unroll
    for (int mask = 1; mask < SEG; mask <<= 1) {
        const uint64_t r0 = shfl_xor_u64(b0, mask);
        const uint64_t r1 = shfl_xor_u64(b1, mask);
        const uint64_t r2 = shfl_xor_u64(b2, mask);
        ins_dedup(r0, b0, b1, b2);
        ins_dedup(r1, b0, b1, b2);
        ins_dedup(r2, b0, b1, b2);
    }
}

__global__ __launch_bounds__(QBLK) void knn_query_fb(
    const float* __restrict__ x, const float* __restrict__ pos_x,
    const float* __restrict__ pos_y,
    const float4* __restrict__ wspt, const int* __restrict__ wsidx,
    const int* __restrict__ wcstart,
    float* __restrict__ out, int ny)
{
    __shared__ float4 spt[NXP];
    __shared__ int    sidx[NXP];
    __shared__ int    cstart[NCELL + 1];

    const int t = threadIdx.x;
    for (int i = t; i < NXP; i += QBLK) spt[i] = wspt[i];
    for (int i = t; i < NXP; i += QBLK) sidx[i] = wsidx[i];
    for (int i = t; i < NCELL + 1; i += QBLK) cstart[i] = wcstart[i];
    __syncthreads();

    const int s = t & (SEG - 1);
    const int nbatch = (ny + QPB - 1) / QPB;

    for (int batch = blockIdx.x; batch < nbatch; batch += gridDim.x) {
        const int q = batch * QPB + (t >> 3);
        if (q >= ny) continue;

        const float y0 = pos_y[q*3+0], y1 = pos_y[q*3+1], y2 = pos_y[q*3+2];
        const float sy = __fadd_rn(__fadd_rn(__fmul_rn(y0, y0), __fmul_rn(y1, y1)),
                                   __fmul_rn(y2, y2));
        const int cx = cell_of(y0), cy = cell_of(y1), cz = cell_of(y2);

        uint64_t b0 = ~0ull, b1 = ~0ull, b2 = ~0ull;

#define EVAL_BODY(P, INS)                                                       \
        {                                                                       \
            const float4 pt = spt[P];                                           \
            const float dot = __fmaf_rn(y2, pt.z,                               \
                              __fmaf_rn(y1, pt.y, __fmul_rn(y0, pt.x)));        \
            const float d = __fmaf_rn(-2.0f, dot, __fadd_rn(sy, pt.w));         \
            const uint64_t kk = ((uint64_t)mono(d) << 32) | (uint32_t)sidx[P];  \
            if (kk < b2) INS(kk, b0, b1, b2);                                   \
        }

        const int x0 = cx - 1 < 0 ? 0 : cx - 1;
        const int x1 = cx + 1 > GD - 1 ? GD - 1 : cx + 1;
        #pragma unroll
        for (int r = 0; r < 9; ++r) {
            const int uz = cz + r / 3 - 1, uy = cy + r % 3 - 1;
            int st = 0, en = 0;
            if (((unsigned)uz < (unsigned)GD) & ((unsigned)uy < (unsigned)GD)) {
                const int cb = (uz * GD + uy) * GD;
                st = cstart[cb + x0];
                en = cstart[cb + x1 + 1];
            }
            for (int p = st + s; p < en; p += SEG) EVAL_BODY(p, ins_fast)
        }
        merge_group8(b0, b1, b2);

        {
            bool have3 = (b2 != ~0ull);
            float b2d = unmono((uint32_t)(b2 >> 32));
            if (!(have3 && (b2d + 1e-4f < 0.015625f))) {
                for (int r = 0; r < 25; ++r) {
                    const int dzi = r / 5 - 2, dyi = r % 5 - 2;
                    const int uz = cz + dzi, uy = cy + dyi;
                    if (((unsigned)uz >= (unsigned)GD) | ((unsigned)uy >= (unsigned)GD))
                        continue;
                    const int cb = (uz * GD + uy) * GD;
                    if (dzi == -2 || dzi == 2 || dyi == -2 || dyi == 2) {
                        const int xa = cx - 2 < 0 ? 0 : cx - 2;
                        const int xb = cx + 2 > GD - 1 ? GD - 1 : cx + 2;
                        const int st = cstart[cb + xa], en = cstart[cb + xb + 1];
                        for (int p = st + s; p < en; p += SEG) EVAL_BODY(p, ins_fast)
                    } else {
                        if (cx - 2 >= 0) {
                            const int st = cstart[cb + cx - 2], en = cstart[cb + cx - 1];
                            for (int p = st + s; p < en; p += SEG) EVAL_BODY(p, ins_fast)
                        }
                        if (cx + 2 <= GD - 1) {
                            const int st = cstart[cb + cx + 2], en = cstart[cb + cx + 3];
                            for (int p = st + s; p < en; p += SEG) EVAL_BODY(p, ins_fast)
                        }
                    }
                }
                merge_group8(b0, b1, b2);

                have3 = (b2 != ~0ull);
                b2d = unmono((uint32_t)(b2 >> 32));
                if (!(have3 && (b2d + 1e-4f < 0.0625f))) {
                    for (int p = s; p < NXP; p += SEG) EVAL_BODY(p, ins_dedup)
                    merge_group8(b0, b1, b2);
                }
            }
        }
#undef EVAL_BODY

        const int j[3] = { (int)(uint32_t)b0, (int)(uint32_t)b1, (int)(uint32_t)b2 };
        float w[3];
        #pragma unroll
        for (int i = 0; i < 3; ++i) {
            const int jj = j[i];
            const float dx = __fsub_rn(pos_x[jj*3+0], y0);
            const float dy = __fsub_rn(pos_x[jj*3+1], y1);
            const float dz = __fsub_rn(pos_x[jj*3+2], y2);
            const float sq = __fadd_rn(__fadd_rn(__fmul_rn(dx, dx), __fmul_rn(dy, dy)),
                                       __fmul_rn(dz, dz));
            w[i] = 1.0f / fmaxf(sq, 1e-16f);
        }
        const float inv_den = 1.0f / __fadd_rn(__fadd_rn(w[0], w[1]), w[2]);

        const float2* x2 = (const float2*)x;
        float2* o2 = (float2*)out;
        const float2 a = x2[j[0]*8 + s];
        const float2 b = x2[j[1]*8 + s];
        const float2 c = x2[j[2]*8 + s];
        float2 rr;
        rr.x = (w[0]*a.x + w[1]*b.x + w[2]*c.x) * inv_den;
        rr.y = (w[0]*a.y + w[1]*b.y + w[2]*c.y) * inv_den;
        o2[q*8 + s] = rr;
    }
}

extern "C" void kernel_launch(void* const* d_in, const int* in_sizes, int n_in,
                              void* d_out, int out_size, void* d_ws, size_t ws_size,
                              hipStream_t stream) {
    const float* x     = (const float*)d_in[0];  // [2048, 16]
    const float* pos_x = (const float*)d_in[1];  // [2048, 3]
    const float* pos_y = (const float*)d_in[2];  // [65536, 3]
    float* out = (float*)d_out;
    const int ny = in_sizes[2] / 3;  // 65536

    float4*         wspt   = (float4*)        ((char*)d_ws + WS_SPT);
    int*            wsidx  = (int*)           ((char*)d_ws + WS_SIDX);
    int*            wcst   = (int*)           ((char*)d_ws + WS_CST);
    unsigned short* scan2d = (unsigned short*)((char*)d_ws + WS_SCN);
    unsigned short* qsrt   = (unsigned short*)((char*)d_ws + WS_QSRT);

    if (ws_size >= (size_t)WS_NEED && ny <= NQB * BQ) {
        build_scatter<<<1 + NQB, 512, 0, stream>>>(pos_x, pos_y, ny,
                                                   wspt, wsidx, wcst, scan2d, qsrt);
        knn_cell<<<NCELL, 512, 0, stream>>>(x, pos_x, pos_y, wspt, wsidx, wcst,
                                            scan2d, qsrt, out);
    } else {
        build_scatter<<<1, 512, 0, stream>>>(pos_x, pos_y, 0,
                                             wspt, wsidx, wcst, scan2d, qsrt);
        knn_query_fb<<<QGRID, QBLK, 0, stream>>>(x, pos_x, pos_y, wspt, wsidx, wcst,
                                                 out, ny);
    }
}

// Round 16
// 28.235 us; speedup vs baseline: 3.3686x; 1.1899x over previous
//
#include <hip/hip_runtime.h>
#include <stdint.h>

#define NXP   2048   // pivotal (source) nodes
#define NC    16     // feature channels
#define GD    8      // grid cells per axis
#define NCELL (GD*GD*GD)   // 512
#define CAP   512    // max staged candidates per cell block
#define QCAP  512    // query LDS list capacity per pass
#define HCELL 0.125f
#define NQB   128    // query scatter blocks
#define BQ    512    // queries per scatter block

// ---- d_ws layout (bytes); total 305472 <= 312832 (proven available, r9) ----
#define WS_SPT   0        // float4[2048]
#define WS_SIDX  32768    // int[2048]
#define WS_CST   40960    // int[513]                     (ends 43012)
#define WS_SCN   43072    // u16[128][513] per-block cell scan (ends 174400)
#define WS_QSRT  174400   // u16[65536] block-sorted query ids (ends 305472)
#define WS_NEED  305472

__device__ __forceinline__ int cell_of(float v) {
    int c = (int)(v * (float)GD);
    c = c > GD - 1 ? GD - 1 : c;
    return c < 0 ? 0 : c;
}
__device__ __forceinline__ uint32_t mono(float d) {
    uint32_t b = __float_as_uint(d);
    return b ^ (uint32_t)(((int32_t)b >> 31) | 0x80000000);
}
__device__ __forceinline__ float unmono(uint32_t m) {
    uint32_t b = (m & 0x80000000u) ? (m ^ 0x80000000u) : ~m;
    return __uint_as_float(b);
}
__device__ __forceinline__ void ins_fast(uint64_t k, uint64_t& b0, uint64_t& b1, uint64_t& b2) {
    const bool lt0 = k < b0, lt1 = k < b1;
    b2 = lt1 ? b1 : k;
    b1 = lt0 ? b0 : (lt1 ? k : b1);
    b0 = lt0 ? k  : b0;
}
__device__ __forceinline__ void ins_dedup(uint64_t k, uint64_t& b0, uint64_t& b1, uint64_t& b2) {
    if (k == b0 || k == b1 || k == b2) return;
    const bool lt0 = k < b0, lt1 = k < b1, lt2 = k < b2;
    b2 = lt1 ? b1 : (lt2 ? k : b2);
    b1 = lt0 ? b0 : (lt1 ? k : b1);
    b0 = lt0 ? k  : b0;
}
__device__ __forceinline__ uint64_t shfl_u64(uint64_t v, int src) {
    const int lo = __shfl((int)(uint32_t)v, src);
    const int hi = __shfl((int)(uint32_t)(v >> 32), src);
    return ((uint64_t)(uint32_t)hi << 32) | (uint32_t)lo;
}
__device__ __forceinline__ uint64_t shfl_xor_u64(uint64_t v, int mask) {
    const int lo = __shfl_xor((int)(uint32_t)v, mask);
    const int hi = __shfl_xor((int)(uint32_t)(v >> 32), mask);
    return ((uint64_t)(uint32_t)hi << 32) | (uint32_t)lo;
}

// ========== K1: block 0 builds point grid; blocks 1..128 LDS-sort queries ==========
__global__ __launch_bounds__(512) void build_scatter(
    const float* __restrict__ pos_x, const float* __restrict__ pos_y, int ny,
    float4* __restrict__ wspt, int* __restrict__ wsidx, int* __restrict__ wcstart,
    unsigned short* __restrict__ scan2d, unsigned short* __restrict__ qsrt)
{
    __shared__ int sA[NCELL];
    __shared__ int sB[NCELL];
    const int t = threadIdx.x;

    if (blockIdx.x == 0) {
        // ---- point grid build (byte-identical to proven r6..r15 code) ----
        sA[t] = 0;
        __syncthreads();

        const float4* px4 = (const float4*)pos_x;
        const float4 v0 = px4[t*3+0], v1 = px4[t*3+1], v2 = px4[t*3+2];
        const float pxx[4] = {v0.x, v0.w, v1.z, v2.y};
        const float pyy[4] = {v0.y, v1.x, v1.w, v2.z};
        const float pzz[4] = {v0.z, v1.y, v2.x, v2.w};
        int cc[4];
        #pragma unroll
        for (int i = 0; i < 4; ++i) {
            cc[i] = (cell_of(pzz[i]) * GD + cell_of(pyy[i])) * GD + cell_of(pxx[i]);
            atomicAdd(&sA[cc[i]], 1);
        }
        __syncthreads();

        if (t < 64) {
            const int base = t * 8;
            int v[8];
            int run = 0;
            #pragma unroll
            for (int i = 0; i < 8; ++i) { run += sA[base + i]; v[i] = run; }
            int xs = run;
            #pragma unroll
            for (int off = 1; off < 64; off <<= 1) {
                const int y = __shfl_up(xs, off);
                if (t >= off) xs += y;
            }
            const int excl = xs - run;
            #pragma unroll
            for (int i = 0; i < 8; ++i) {
                const int inc = excl + v[i];
                wcstart[base + i + 1] = inc;
                sB[base + i] = inc - sA[base + i];
            }
            if (t == 0) wcstart[0] = 0;
        }
        __syncthreads();

        #pragma unroll
        for (int i = 0; i < 4; ++i) {
            const int p = t * 4 + i;
            const int pos = atomicAdd(&sB[cc[i]], 1);
            const float sx = __fadd_rn(__fadd_rn(__fmul_rn(pxx[i], pxx[i]),
                                                 __fmul_rn(pyy[i], pyy[i])),
                                       __fmul_rn(pzz[i], pzz[i]));
            wspt[pos] = make_float4(pxx[i], pyy[i], pzz[i], sx);
            wsidx[pos] = p;
        }
    } else {
        // ---- LDS counting sort of this block's 512 queries (no global atomics) ----
        const int b = blockIdx.x - 1;
        sA[t] = 0;
        __syncthreads();

        const int q = b * BQ + t;
        int c = -1;
        if (q < ny) {
            c = (cell_of(pos_y[q*3+2]) * GD + cell_of(pos_y[q*3+1])) * GD
              + cell_of(pos_y[q*3+0]);
            atomicAdd(&sA[c], 1);     // LDS atomic
        }
        __syncthreads();

        if (t < 64) {
            const int base = t * 8;
            int v[8];
            int run = 0;
            #pragma unroll
            for (int i = 0; i < 8; ++i) { run += sA[base + i]; v[i] = run; }
            int xs = run;
            #pragma unroll
            for (int off = 1; off < 64; off <<= 1) {
                const int y = __shfl_up(xs, off);
                if (t >= off) xs += y;
            }
            const int excl = xs - run;
            #pragma unroll
            for (int i = 0; i < 8; ++i)
                sB[base + i] = excl + v[i] - sA[base + i];   // exclusive start
        }
        __syncthreads();

        scan2d[b * 513 + t] = (unsigned short)sB[t];
        if (t == 0) {
            int nb = ny - b * BQ;
            nb = nb < 0 ? 0 : (nb > BQ ? BQ : nb);
            scan2d[b * 513 + 512] = (unsigned short)nb;
        }
        __syncthreads();

        if (q < ny) {
            const int pos = atomicAdd(&sB[c], 1);   // LDS atomic rank
            qsrt[b * BQ + pos] = (unsigned short)q;
        }
    }
}

// ========== K2: TWO blocks per cell (half the queries each); 4-lane groups ==========
__global__ __launch_bounds__(256) void knn_cell(
    const float* __restrict__ x, const float* __restrict__ pos_x,
    const float* __restrict__ pos_y,
    const float4* __restrict__ wspt, const int* __restrict__ wsidx,
    const int* __restrict__ wcst,
    const unsigned short* __restrict__ scan2d, const unsigned short* __restrict__ qsrt,
    float* __restrict__ out)
{
    __shared__ float4 scand[CAP];
    __shared__ int    scidx[CAP];
    __shared__ int    rst[25], roff[26];
    __shared__ int    sL, sForce;
    __shared__ unsigned short qlist[QCAP];
    __shared__ int    wsum[2];

    const int t = threadIdx.x;
    const int c = blockIdx.x >> 1, half = blockIdx.x & 1;
    const int cx = c & 7, cy = (c >> 3) & 7, cz = c >> 6;
    const int lane = t & 63;   // lane in wave
    const int grp  = t >> 2;   // query group 0..63
    const int s    = t & 3;    // segment within group

    // R=2 only for edge/corner cells (bcnt>=2) — r6/r7-proven rule
    const int bcnt = (int)(cx == 0 || cx == GD-1) + (int)(cy == 0 || cy == GD-1)
                   + (int)(cz == 0 || cz == GD-1);
    const int R  = (bcnt >= 2) ? 2 : 1;
    const int W  = 2 * R + 1;
    const int NR = W * W;

    if (t < NR) {
        const int uz = cz + t / W - R, uy = cy + t % W - R;
        int st = 0, len = 0;
        if (((unsigned)uz < (unsigned)GD) & ((unsigned)uy < (unsigned)GD)) {
            const int xa = cx - R < 0 ? 0 : cx - R;
            const int xb = cx + R > GD - 1 ? GD - 1 : cx + R;
            const int cb = (uz * GD + uy) * GD;
            st  = wcst[cb + xa];
            len = wcst[cb + xb + 1] - st;
        }
        rst[t] = st;
        roff[t] = len;
    }
    __syncthreads();
    if (t == 0) {
        int o = 0;
        #pragma unroll 1
        for (int r = 0; r < NR; ++r) { const int l = roff[r]; roff[r] = o; o += l; }
        roff[NR] = o;
        sL = o > CAP ? CAP : o;
        sForce = (o > CAP) ? 1 : 0;
    }
    __syncthreads();

    // Lpad multiple of 32 (per-lane count multiple of 8); (512+31)&~31 == 512 <= CAP
    const int L = sL, Lpad = (sL + 31) & ~31, force = sForce;
    for (int i = t; i < L; i += 256) {
        int r = 0;
        while (i >= roff[r + 1]) ++r;
        const int src = rst[r] + (i - roff[r]);
        scand[i] = wspt[src];
        scidx[i] = wsidx[src];
    }
    for (int i = L + t; i < Lpad; i += 256) {
        scand[i] = make_float4(0.f, 0.f, 0.f, 3e30f);  // sentinel: never inserted
        scidx[i] = 0x7fffffff;
    }

    // ---- query gather (threads 0..127): lane t = source block; seg [s0, s0+cnt) ----
    int base = 0, cnt = 0, s0 = 0;
    if (t < 128) {
        s0  = (int)scan2d[t * 513 + c];
        cnt = (int)scan2d[t * 513 + c + 1] - s0;
        int inc = cnt;
        #pragma unroll
        for (int off = 1; off < 64; off <<= 1) {
            const int y = __shfl_up(inc, off);
            if (lane >= off) inc += y;
        }
        if (lane == 63) wsum[t >> 6] = inc;
        base = inc - cnt;
    }
    __syncthreads();
    if (t >= 64 && t < 128) base += wsum[0];
    const int total = wsum[0] + wsum[1];

    // this block handles [beg, end) of the cell's query list
    const int mid = (total + 1) >> 1;
    const int beg = half ? mid : 0;
    const int end = half ? total : mid;

    for (int S = 0; S < total; S += QCAP) {
        __syncthreads();
        if (t < 128) {
            for (int k = 0; k < cnt; ++k) {
                const int g = base + k;
                if (g >= S && g < S + QCAP) qlist[g - S] = qsrt[t * BQ + s0 + k];
            }
        }
        __syncthreads();
        // intersect this chunk with [beg, end)
        const int n   = (total - S) < QCAP ? (total - S) : QCAP;
        const int lo  = (beg - S) > 0 ? (beg - S) : 0;
        const int hi  = (end - S) < n ? (end - S) : n;

        for (int i0 = lo; i0 < hi; i0 += 64) {
            const int slot = i0 + grp;
            const bool active = slot < hi;
            const int q = active ? (int)qlist[slot] : 0;
            float y0 = 0.f, y1 = 0.f, y2 = 0.f;
            if (active) { y0 = pos_y[q*3+0]; y1 = pos_y[q*3+1]; y2 = pos_y[q*3+2]; }
            const float sy = __fadd_rn(__fadd_rn(__fmul_rn(y0, y0), __fmul_rn(y1, y1)),
                                       __fmul_rn(y2, y2));

            // exact clearance to staged cube (proven r9..r15)
            float clr = 1e30f;
            if (cx - R > 0)      clr = fminf(clr, y0 - (float)(cx - R) * HCELL);
            if (cx + R < GD - 1) clr = fminf(clr, (float)(cx + R + 1) * HCELL - y0);
            if (cy - R > 0)      clr = fminf(clr, y1 - (float)(cy - R) * HCELL);
            if (cy + R < GD - 1) clr = fminf(clr, (float)(cy + R + 1) * HCELL - y1);
            if (cz - R > 0)      clr = fminf(clr, y2 - (float)(cz - R) * HCELL);
            if (cz + R < GD - 1) clr = fminf(clr, (float)(cz + R + 1) * HCELL - y2);
            const float thr = clr * clr;

            uint64_t b0 = ~0ull, b1 = ~0ull, b2 = ~0ull;

            // ---- phase A: lane scans its quarter (stride-4 interleave),
            // 2-deep pipeline over 4-candidate batches; d2 rounding identical
            // to every passing round.
            const int PL = Lpad >> 2;    // per-lane candidates, multiple of 8
            float4 pA[4]; int iA[4];
            float4 pB[4]; int iB[4];
            #pragma unroll
            for (int u = 0; u < 4; ++u) {
                const int id = s + 4*u;
                pA[u] = scand[id]; iA[u] = scidx[id];
            }

            for (int j = 0; j < PL; j += 8) {
                #pragma unroll
                for (int u = 0; u < 4; ++u) {
                    const int id = s + 4*(j + 4 + u);
                    pB[u] = scand[id]; iB[u] = scidx[id];
                }
                {
                    uint64_t kk[4];
                    #pragma unroll
                    for (int u = 0; u < 4; ++u) {
                        const float dot = __fmaf_rn(y2, pA[u].z,
                                          __fmaf_rn(y1, pA[u].y, __fmul_rn(y0, pA[u].x)));
                        const float d = __fmaf_rn(-2.0f, dot, __fadd_rn(sy, pA[u].w));
                        kk[u] = ((uint64_t)mono(d) << 32) | (uint32_t)iA[u];
                    }
                    #pragma unroll
                    for (int u = 0; u < 4; ++u) {
                        const uint64_t k2 = kk[u];
                        const bool lt0 = k2 < b0, lt1 = k2 < b1, lt2 = k2 < b2;
                        b2 = lt1 ? b1 : (lt2 ? k2 : b2);
                        b1 = lt0 ? b0 : (lt1 ? k2 : b1);
                        b0 = lt0 ? k2 : b0;
                    }
                }
                if (j + 8 < PL) {
                    #pragma unroll
                    for (int u = 0; u < 4; ++u) {
                        const int id = s + 4*(j + 8 + u);
                        pA[u] = scand[id]; iA[u] = scidx[id];
                    }
                }
                {
                    uint64_t kk[4];
                    #pragma unroll
                    for (int u = 0; u < 4; ++u) {
                        const float dot = __fmaf_rn(y2, pB[u].z,
                                          __fmaf_rn(y1, pB[u].y, __fmul_rn(y0, pB[u].x)));
                        const float d = __fmaf_rn(-2.0f, dot, __fadd_rn(sy, pB[u].w));
                        kk[u] = ((uint64_t)mono(d) << 32) | (uint32_t)iB[u];
                    }
                    #pragma unroll
                    for (int u = 0; u < 4; ++u) {
                        const uint64_t k2 = kk[u];
                        const bool lt0 = k2 < b0, lt1 = k2 < b1, lt2 = k2 < b2;
                        b2 = lt1 ? b1 : (lt2 ? k2 : b2);
                        b1 = lt0 ? b0 : (lt1 ? k2 : b1);
                        b0 = lt0 ? k2 : b0;
                    }
                }
            }

            // merge across the 4-lane group (masks 1,2 stay in-group); dedup
            // makes overlap-free merging safe (r5-proven)
            #pragma unroll
            for (int mask = 1; mask < 4; mask <<= 1) {
                const uint64_t r0 = shfl_xor_u64(b0, mask);
                const uint64_t r1 = shfl_xor_u64(b1, mask);
                const uint64_t r2 = shfl_xor_u64(b2, mask);
                ins_dedup(r0, b0, b1, b2);
                ins_dedup(r1, b0, b1, b2);
                ins_dedup(r2, b0, b1, b2);
            }

            // escalation (proven): only group leader flags; wave-coop brute
            bool esc = false;
            if (active && s == 0) {
                const bool have3 = (b2 != ~0ull);
                const float b2d = unmono((uint32_t)(b2 >> 32));
                esc = !(have3 && (b2d + 1e-4f < thr)) | (force != 0);
            }
            unsigned long long bal = __ballot(esc);
            while (bal) {
                const int e = __ffsll(bal) - 1;
                bal &= bal - 1;
                const float ey0 = __shfl(y0, e), ey1 = __shfl(y1, e), ey2 = __shfl(y2, e);
                const float esy = __shfl(sy, e);
                uint64_t m0 = shfl_u64(b0, e), m1 = shfl_u64(b1, e), m2 = shfl_u64(b2, e);
                for (int p = lane; p < NXP; p += 64) {
                    const float4 pt = wspt[p];
                    const float dot = __fmaf_rn(ey2, pt.z,
                                      __fmaf_rn(ey1, pt.y, __fmul_rn(ey0, pt.x)));
                    const float d = __fmaf_rn(-2.0f, dot, __fadd_rn(esy, pt.w));
                    const uint64_t kk = ((uint64_t)mono(d) << 32) | (uint32_t)wsidx[p];
                    if (kk < m2) ins_dedup(kk, m0, m1, m2);
                }
                #pragma unroll
                for (int mask = 1; mask < 64; mask <<= 1) {
                    const uint64_t r0 = shfl_xor_u64(m0, mask);
                    const uint64_t r1 = shfl_xor_u64(m1, mask);
                    const uint64_t r2 = shfl_xor_u64(m2, mask);
                    ins_dedup(r0, m0, m1, m2);
                    ins_dedup(r1, m0, m1, m2);
                    ins_dedup(r2, m0, m1, m2);
                }
                if (lane == e) { b0 = m0; b1 = m1; b2 = m2; }
            }
            // re-broadcast group leader's triple (identity for non-escalated)
            {
                const int ldr = lane & ~3;
                b0 = shfl_u64(b0, ldr);
                b1 = shfl_u64(b1, ldr);
                b2 = shfl_u64(b2, ldr);
            }

            // epilogue: each lane writes channel quarter s (coalesced 64B/query)
            if (active) {
                const int j0 = (int)(uint32_t)b0, j1 = (int)(uint32_t)b1,
                          j2 = (int)(uint32_t)b2;
                float w[3];
                const int jj[3] = { j0, j1, j2 };
                #pragma unroll
                for (int i = 0; i < 3; ++i) {
                    const float dx = __fsub_rn(pos_x[jj[i]*3+0], y0);
                    const float dy = __fsub_rn(pos_x[jj[i]*3+1], y1);
                    const float dz = __fsub_rn(pos_x[jj[i]*3+2], y2);
                    const float sq = __fadd_rn(__fadd_rn(__fmul_rn(dx, dx),
                                                         __fmul_rn(dy, dy)),
                                               __fmul_rn(dz, dz));
                    w[i] = 1.0f / fmaxf(sq, 1e-16f);
                }
                const float inv_den = 1.0f / __fadd_rn(__fadd_rn(w[0], w[1]), w[2]);
                const float4* x4 = (const float4*)x;
                float4* o4 = (float4*)out;
                const float4 a = x4[j0*4 + s];
                const float4 b = x4[j1*4 + s];
                const float4 cc2 = x4[j2*4 + s];
                float4 r;
                r.x = (w[0]*a.x + w[1]*b.x + w[2]*cc2.x) * inv_den;
                r.y = (w[0]*a.y + w[1]*b.y + w[2]*cc2.y) * inv_den;
                r.z = (w[0]*a.z + w[1]*b.z + w[2]*cc2.z) * inv_den;
                r.w = (w[0]*a.w + w[1]*b.w + w[2]*cc2.w) * inv_den;
                o4[q*4 + s] = r;
            }
        }
    }
}

// =============== fallback (round-7 kernel, 43 KB ws; proven 34 us) ===============
#define QBLK  512
#define SEG   8
#define QPB   (QBLK / SEG)
#define QGRID 512

__device__ __forceinline__ void merge_group8(uint64_t& b0, uint64_t& b1, uint64_t& b2) {
    #pragma unroll
    for (int mask = 1; mask < SEG; mask <<= 1) {
        const uint64_t r0 = shfl_xor_u64(b0, mask);
        const uint64_t r1 = shfl_xor_u64(b1, mask);
        const uint64_t r2 = shfl_xor_u64(b2, mask);
        ins_dedup(r0, b0, b1, b2);
        ins_dedup(r1, b0, b1, b2);
        ins_dedup(r2, b0, b1, b2);
    }
}

__global__ __launch_bounds__(QBLK) void knn_query_fb(
    const float* __restrict__ x, const float* __restrict__ pos_x,
    const float* __restrict__ pos_y,
    const float4* __restrict__ wspt, const int* __restrict__ wsidx,
    const int* __restrict__ wcstart,
    float* __restrict__ out, int ny)
{
    __shared__ float4 spt[NXP];
    __shared__ int    sidx[NXP];
    __shared__ int    cstart[NCELL + 1];

    const int t = threadIdx.x;
    for (int i = t; i < NXP; i += QBLK) spt[i] = wspt[i];
    for (int i = t; i < NXP; i += QBLK) sidx[i] = wsidx[i];
    for (int i = t; i < NCELL + 1; i += QBLK) cstart[i] = wcstart[i];
    __syncthreads();

    const int s = t & (SEG - 1);
    const int nbatch = (ny + QPB - 1) / QPB;

    for (int batch = blockIdx.x; batch < nbatch; batch += gridDim.x) {
        const int q = batch * QPB + (t >> 3);
        if (q >= ny) continue;

        const float y0 = pos_y[q*3+0], y1 = pos_y[q*3+1], y2 = pos_y[q*3+2];
        const float sy = __fadd_rn(__fadd_rn(__fmul_rn(y0, y0), __fmul_rn(y1, y1)),
                                   __fmul_rn(y2, y2));
        const int cx = cell_of(y0), cy = cell_of(y1), cz = cell_of(y2);

        uint64_t b0 = ~0ull, b1 = ~0ull, b2 = ~0ull;

#define EVAL_BODY(P, INS)                                                       \
        {                                                                       \
            const float4 pt = spt[P];                                           \
            const float dot = __fmaf_rn(y2, pt.z,                               \
                              __fmaf_rn(y1, pt.y, __fmul_rn(y0, pt.x)));        \
            const float d = __fmaf_rn(-2.0f, dot, __fadd_rn(sy, pt.w));         \
            const uint64_t kk = ((uint64_t)mono(d) << 32) | (uint32_t)sidx[P];  \
            if (kk < b2) INS(kk, b0, b1, b2);                                   \
        }

        const int x0 = cx - 1 < 0 ? 0 : cx - 1;
        const int x1 = cx + 1 > GD - 1 ? GD - 1 : cx + 1;
        #pragma unroll
        for (int r = 0; r < 9; ++r) {
            const int uz = cz + r / 3 - 1, uy = cy + r % 3 - 1;
            int st = 0, en = 0;
            if (((unsigned)uz < (unsigned)GD) & ((unsigned)uy < (unsigned)GD)) {
                const int cb = (uz * GD + uy) * GD;
                st = cstart[cb + x0];
                en = cstart[cb + x1 + 1];
            }
            for (int p = st + s; p < en; p += SEG) EVAL_BODY(p, ins_fast)
        }
        merge_group8(b0, b1, b2);

        {
            bool have3 = (b2 != ~0ull);
            float b2d = unmono((uint32_t)(b2 >> 32));
            if (!(have3 && (b2d + 1e-4f < 0.015625f))) {
                for (int r = 0; r < 25; ++r) {
                    const int dzi = r / 5 - 2, dyi = r % 5 - 2;
                    const int uz = cz + dzi, uy = cy + dyi;
                    if (((unsigned)uz >= (unsigned)GD) | ((unsigned)uy >= (unsigned)GD))
                        continue;
                    const int cb = (uz * GD + uy) * GD;
                    if (dzi == -2 || dzi == 2 || dyi == -2 || dyi == 2) {
                        const int xa = cx - 2 < 0 ? 0 : cx - 2;
                        const int xb = cx + 2 > GD - 1 ? GD - 1 : cx + 2;
                        const int st = cstart[cb + xa], en = cstart[cb + xb + 1];
                        for (int p = st + s; p < en; p += SEG) EVAL_BODY(p, ins_fast)
                    } else {
                        if (cx - 2 >= 0) {
                            const int st = cstart[cb + cx - 2], en = cstart[cb + cx - 1];
                            for (int p = st + s; p < en; p += SEG) EVAL_BODY(p, ins_fast)
                        }
                        if (cx + 2 <= GD - 1) {
                            const int st = cstart[cb + cx + 2], en = cstart[cb + cx + 3];
                            for (int p = st + s; p < en; p += SEG) EVAL_BODY(p, ins_fast)
                        }
                    }
                }
                merge_group8(b0, b1, b2);

                have3 = (b2 != ~0ull);
                b2d = unmono((uint32_t)(b2 >> 32));
                if (!(have3 && (b2d + 1e-4f < 0.0625f))) {
                    for (int p = s; p < NXP; p += SEG) EVAL_BODY(p, ins_dedup)
                    merge_group8(b0, b1, b2);
                }
            }
        }
#undef EVAL_BODY

        const int j[3] = { (int)(uint32_t)b0, (int)(uint32_t)b1, (int)(uint32_t)b2 };
        float w[3];
        #pragma unroll
        for (int i = 0; i < 3; ++i) {
            const int jj = j[i];
            const float dx = __fsub_rn(pos_x[jj*3+0], y0);
            const float dy = __fsub_rn(pos_x[jj*3+1], y1);
            const float dz = __fsub_rn(pos_x[jj*3+2], y2);
            const float sq = __fadd_rn(__fadd_rn(__fmul_rn(dx, dx), __fmul_rn(dy, dy)),
                                       __fmul_rn(dz, dz));
            w[i] = 1.0f / fmaxf(sq, 1e-16f);
        }
        const float inv_den = 1.0f / __fadd_rn(__fadd_rn(w[0], w[1]), w[2]);

        const float2* x2 = (const float2*)x;
        float2* o2 = (float2*)out;
        const float2 a = x2[j[0]*8 + s];
        const float2 b = x2[j[1]*8 + s];
        const float2 c = x2[j[2]*8 + s];
        float2 rr;
        rr.x = (w[0]*a.x + w[1]*b.x + w[2]*c.x) * inv_den;
        rr.y = (w[0]*a.y + w[1]*b.y + w[2]*c.y) * inv_den;
        o2[q*8 + s] = rr;
    }
}

extern "C" void kernel_launch(void* const* d_in, const int* in_sizes, int n_in,
                              void* d_out, int out_size, void* d_ws, size_t ws_size,
                              hipStream_t stream) {
    const float* x     = (const float*)d_in[0];  // [2048, 16]
    const float* pos_x = (const float*)d_in[1];  // [2048, 3]
    const float* pos_y = (const float*)d_in[2];  // [65536, 3]
    float* out = (float*)d_out;
    const int ny = in_sizes[2] / 3;  // 65536

    float4*         wspt   = (float4*)        ((char*)d_ws + WS_SPT);
    int*            wsidx  = (int*)           ((char*)d_ws + WS_SIDX);
    int*            wcst   = (int*)           ((char*)d_ws + WS_CST);
    unsigned short* scan2d = (unsigned short*)((char*)d_ws + WS_SCN);
    unsigned short* qsrt   = (unsigned short*)((char*)d_ws + WS_QSRT);

    if (ws_size >= (size_t)WS_NEED && ny <= NQB * BQ) {
        build_scatter<<<1 + NQB, 512, 0, stream>>>(pos_x, pos_y, ny,
                                                   wspt, wsidx, wcst, scan2d, qsrt);
        knn_cell<<<NCELL * 2, 256, 0, stream>>>(x, pos_x, pos_y, wspt, wsidx, wcst,
                                                scan2d, qsrt, out);
    } else {
        build_scatter<<<1, 512, 0, stream>>>(pos_x, pos_y, 0,
                                             wspt, wsidx, wcst, scan2d, qsrt);
        knn_query_fb<<<QGRID, QBLK, 0, stream>>>(x, pos_x, pos_y, wspt, wsidx, wcst,
                                                 out, ny);
    }
}